// Round 14
// baseline (1933.846 us; speedup 1.0000x reference)
//
#include <hip/hip_runtime.h>
#include <hip/hip_bf16.h>

typedef __bf16 bf16x8 __attribute__((ext_vector_type(8)));
typedef float  f32x4  __attribute__((ext_vector_type(4)));

#define SCHUNK 2048  // elements per scan1 block (256 thr * 8)

struct EdgeArgs {
    const int* ei[9];
    int E[9];
    int ebase[10];   // prefix over edges
    int binbase[9];  // prefix over dst bins
};

struct ConvGroup {          // 3 convs sharing the same dst type
    const int* rowptr[3];
    const __bf16* xsrc[3];
    const __bf16* agg[3];   // pre-gathered A (unfused convs)
    const __bf16* Wp[3];
    const float* bias[3];
    float* stats[3];
    __bf16* hout[3];
    const __bf16* xdst;
    const int* csr;
    int fused[3];
    int M;
};

struct NormGroup {
    const __bf16* h[3];
    const float* stats[3];
    const float* gamma[3];
    const float* beta[3];
    const float* resid;     // f32 base (L1) or null
    void* out;
    float invM;
    int M;
};

// ---------------------------------------------------------------- pack W
// Layout: [li=L*9+i][ks(8)][cf(8)][lane(64)][j(8)]  (bf16)
// k = ks*32 + (lane>>4)*8 + j ; col = cf*16 + (lane&15)
__global__ void __launch_bounds__(256) pack_w(const float* __restrict__ Wrel,
                                              const float* __restrict__ Wroot,
                                              __bf16* __restrict__ Wp)
{
    const int idx = blockIdx.x * 256 + threadIdx.x;
    if (idx >= 2 * 9 * 8 * 8 * 64) return;
    const int lane = idx & 63;
    int t = idx >> 6;
    const int cf = t & 7; t >>= 3;
    const int ks = t & 7; t >>= 3;
    const int li = t;  // 0..17
    const int col = cf * 16 + (lane & 15);
    const int kb  = ks * 32 + (lane >> 4) * 8;
    bf16x8 o;
#pragma unroll
    for (int j = 0; j < 8; ++j) {
        const int k = kb + j;
        const float v = (k < 128)
            ? Wrel [((size_t)li * 128 + k)        * 128 + col]
            : Wroot[((size_t)li * 128 + (k - 128)) * 128 + col];
        o[j] = (__bf16)v;
    }
    *reinterpret_cast<bf16x8*>(Wp + (size_t)idx * 8) = o;
}

// ---------------------------------------------------------------- f32 -> bf16 convert
__global__ void __launch_bounds__(256) cvt_kernel(const float* __restrict__ in,
                                                  __bf16* __restrict__ out, int n8)
{
    int i = blockIdx.x * 256 + threadIdx.x;
    const int stride = gridDim.x * 256;
    for (; i < n8; i += stride) {
        const float4 f0 = *reinterpret_cast<const float4*>(in + (size_t)i * 8);
        const float4 f1 = *reinterpret_cast<const float4*>(in + (size_t)i * 8 + 4);
        bf16x8 o;
        o[0] = (__bf16)f0.x; o[1] = (__bf16)f0.y; o[2] = (__bf16)f0.z; o[3] = (__bf16)f0.w;
        o[4] = (__bf16)f1.x; o[5] = (__bf16)f1.y; o[6] = (__bf16)f1.z; o[7] = (__bf16)f1.w;
        *reinterpret_cast<bf16x8*>(out + (size_t)i * 8) = o;
    }
}

// ---------------------------------------------------------------- CSR build
__global__ void __launch_bounds__(256) hist_kernel(EdgeArgs ea, int Etot,
                                                   int* __restrict__ deg)
{
    int g = blockIdx.x * 256 + threadIdx.x;
    const int stride = gridDim.x * 256;
    for (; g < Etot; g += stride) {
        int t = 0;
        while (g >= ea.ebase[t + 1]) ++t;
        const int e = g - ea.ebase[t];
        const int dst = __builtin_nontemporal_load(&ea.ei[t][ea.E[t] + e]);
        atomicAdd(&deg[ea.binbase[t] + dst], 1);
    }
}

__global__ void __launch_bounds__(256) scan1_kernel(const int* __restrict__ deg, int n,
                                                    int* __restrict__ rowptr,
                                                    int* __restrict__ bsum)
{
    __shared__ int lds[256];
    const int tid = threadIdx.x;
    const int base = blockIdx.x * SCHUNK + tid * 8;
    int v[8]; int tsum = 0;
#pragma unroll
    for (int j = 0; j < 8; ++j) { v[j] = (base + j < n) ? deg[base + j] : 0; tsum += v[j]; }
    int incl = tsum;
    lds[tid] = incl; __syncthreads();
    for (int off = 1; off < 256; off <<= 1) {
        const int add = (tid >= off) ? lds[tid - off] : 0;
        __syncthreads();
        incl += add; lds[tid] = incl; __syncthreads();
    }
    if (tid == 255) bsum[blockIdx.x] = incl;
    int run = incl - tsum;
#pragma unroll
    for (int j = 0; j < 8; ++j) { if (base + j < n) rowptr[base + j] = run; run += v[j]; }
}

__global__ void __launch_bounds__(256) scan2_kernel(int* __restrict__ bsum, int nb)
{
    __shared__ int lds[256];
    __shared__ int carry_s;
    const int tid = threadIdx.x;
    if (tid == 0) carry_s = 0;
    __syncthreads();
    for (int base = 0; base < nb; base += 256) {
        const int v = (base + tid < nb) ? bsum[base + tid] : 0;
        int incl = v;
        lds[tid] = incl; __syncthreads();
        for (int off = 1; off < 256; off <<= 1) {
            const int add = (tid >= off) ? lds[tid - off] : 0;
            __syncthreads();
            incl += add; lds[tid] = incl; __syncthreads();
        }
        const int total = lds[255];
        const int carry = carry_s;
        if (base + tid < nb) bsum[base + tid] = incl - v + carry;
        __syncthreads();
        if (tid == 0) carry_s = carry + total;
        __syncthreads();
    }
}

__global__ void __launch_bounds__(256) fixup_kernel(int* __restrict__ rowptr,
                                                    const int* __restrict__ bsum, int n,
                                                    int Etot, int* __restrict__ cursor)
{
    int i = blockIdx.x * 256 + threadIdx.x;
    const int stride = gridDim.x * 256;
    if (i == 0) rowptr[n] = Etot;
    for (; i < n; i += stride) {
        const int r = rowptr[i] + bsum[i >> 11];
        rowptr[i] = r; cursor[i] = r;
    }
}

// XCD-sharded placement; nontemporal edge reads keep the streaming re-read from
// evicting the shard's dirty cursor/csr lines out of L2.
__global__ void __launch_bounds__(256) place_kernel(EdgeArgs ea, int Etot, int Nbins,
                                                    int* __restrict__ cursor,
                                                    int* __restrict__ csr)
{
    const int shard = blockIdx.x & 7;
    const int lo = (int)(((long long)shard * Nbins) >> 3);
    const int hi = (int)(((long long)(shard + 1) * Nbins) >> 3);
    int g = (blockIdx.x >> 3) * 256 + threadIdx.x;
    const int stride = (gridDim.x >> 3) * 256;
    for (; g < Etot; g += stride) {
        int t = 0;
        while (g >= ea.ebase[t + 1]) ++t;
        const int e = g - ea.ebase[t];
        const int dst = __builtin_nontemporal_load(&ea.ei[t][ea.E[t] + e]);
        const int gb = ea.binbase[t] + dst;
        if (gb >= lo && gb < hi) {
            const int src = __builtin_nontemporal_load(&ea.ei[t][e]);
            const int pos = atomicAdd(&cursor[gb], 1);
            csr[pos] = src;
        }
    }
}

// ---------------------------------------------------------------- gather64
// wave per dst row (high-degree rows, dst=global): pairwise loads, 8 in flight/wave.
__global__ void __launch_bounds__(256) gather64(const __bf16* __restrict__ x,
                                                const int* __restrict__ rowptr,
                                                const int* __restrict__ csr,
                                                __bf16* __restrict__ agg, int N)
{
    const int lane = threadIdx.x & 63;
    const int l16 = lane & 15, grp = lane >> 4;
    int wv = (blockIdx.x * 256 + threadIdx.x) >> 6;
    const int nwv = (gridDim.x * 256) >> 6;
    for (int row = wv; row < N; row += nwv) {
        const int p0 = rowptr[row], p1 = rowptr[row + 1];
        float acc[8] = {0.f, 0.f, 0.f, 0.f, 0.f, 0.f, 0.f, 0.f};
        int p = p0 + grp * 2;
        for (; p + 2 <= p1; p += 8) {
            const int s0 = csr[p], s1 = csr[p + 1];
            const bf16x8 v0 = *reinterpret_cast<const bf16x8*>(x + (size_t)s0 * 128 + l16 * 8);
            const bf16x8 v1 = *reinterpret_cast<const bf16x8*>(x + (size_t)s1 * 128 + l16 * 8);
#pragma unroll
            for (int j = 0; j < 8; ++j) acc[j] += (float)v0[j] + (float)v1[j];
        }
        if (p < p1) {
            const int s0 = csr[p];
            const bf16x8 v0 = *reinterpret_cast<const bf16x8*>(x + (size_t)s0 * 128 + l16 * 8);
#pragma unroll
            for (int j = 0; j < 8; ++j) acc[j] += (float)v0[j];
        }
#pragma unroll
        for (int j = 0; j < 8; ++j) {
            acc[j] += __shfl_xor(acc[j], 16);
            acc[j] += __shfl_xor(acc[j], 32);
        }
        if (grp == 0) {
            bf16x8 o;
#pragma unroll
            for (int j = 0; j < 8; ++j) o[j] = (__bf16)acc[j];
            *reinterpret_cast<bf16x8*>(agg + (size_t)row * 128 + l16 * 8) = o;
        }
    }
}

// ---------------------------------------------------------------- merged fused gather+GEMM+stats
// R12 structure (8-lane gather groups, 32 chains/block, 4 rows/chain, (256,3) —
// R13's (256,4) forced VGPR 80->64 and spilled 670MB). NEW: the 3 convs of a
// dst-group run INSIDE one block (cj loop) so the shared xdst fragments are
// loaded once instead of 3x, and h stores are nontemporal (write-once stream;
// keep x arrays L3-resident for the random gather).
__global__ void __launch_bounds__(256, 3) fgemm_group(ConvGroup cg)
{
    __shared__ __bf16 atile[128 * 128];   // 32 KB
    __shared__ float lsum[128];
    __shared__ float lsq[128];
    const int M    = cg.M;
    const int tid  = threadIdx.x;
    const int lane = tid & 63;
    const int wv   = tid >> 6;

    const int r0 = blockIdx.x * 128;
    const int lrow  = lane & 15;
    const int klane = (lane >> 4) * 8;

    int  car[2]; bool val[2];
#pragma unroll
    for (int rf = 0; rf < 2; ++rf) {
        const int ar = r0 + wv * 32 + rf * 16 + lrow;
        val[rf] = ar < M;
        car[rf] = val[rf] ? ar : (M - 1);
    }
    bf16x8 z8;
#pragma unroll
    for (int j = 0; j < 8; ++j) z8[j] = (__bf16)0.f;

    // xdst fragments (k=128..255 half of A): loaded ONCE, reused by all 3 convs
    bf16x8 xd[2][4];
#pragma unroll
    for (int rf = 0; rf < 2; ++rf)
#pragma unroll
        for (int kk = 0; kk < 4; ++kk) {
            const bf16x8 av = *reinterpret_cast<const bf16x8*>(
                cg.xdst + (size_t)car[rf] * 128 + kk * 32 + klane);
            xd[rf][kk] = val[rf] ? av : z8;
        }

    for (int cj = 0; cj < 3; ++cj) {
        if (tid < 128) { lsum[tid] = 0.f; lsq[tid] = 0.f; }

        const bool fused = cg.fused[cj] != 0;
        if (fused) {
            const int* __restrict__ rp  = cg.rowptr[cj];
            const int* __restrict__ csr = cg.csr;
            const __bf16* __restrict__ xsrc = cg.xsrc[cj];
            const int grp = tid >> 3, l8 = tid & 7;   // 32 groups of 8 lanes
            int pr[5];
#pragma unroll
            for (int rr = 0; rr < 5; ++rr) {
                int rw = r0 + grp * 4 + rr;
                pr[rr] = rp[rw > M ? M : rw];   // rows >= M collapse to empty ranges
            }
#pragma unroll
            for (int rr = 0; rr < 4; ++rr) {
                const int lr = grp * 4 + rr;
                const int p1 = pr[rr + 1];
                float acc[16];
#pragma unroll
                for (int j = 0; j < 16; ++j) acc[j] = 0.f;
                int p = pr[rr];
                for (; p + 2 <= p1; p += 2) {   // pairwise: 2 csr + 4 row loads in flight
                    const int s0 = csr[p], s1 = csr[p + 1];
                    const __bf16* r0p = xsrc + (size_t)s0 * 128 + l8 * 16;
                    const __bf16* r1p = xsrc + (size_t)s1 * 128 + l8 * 16;
                    const bf16x8 a0 = *reinterpret_cast<const bf16x8*>(r0p);
                    const bf16x8 a1 = *reinterpret_cast<const bf16x8*>(r0p + 8);
                    const bf16x8 b0 = *reinterpret_cast<const bf16x8*>(r1p);
                    const bf16x8 b1 = *reinterpret_cast<const bf16x8*>(r1p + 8);
#pragma unroll
                    for (int j = 0; j < 8; ++j) {
                        acc[j]     += (float)a0[j] + (float)b0[j];
                        acc[8 + j] += (float)a1[j] + (float)b1[j];
                    }
                }
                if (p < p1) {
                    const int s0 = csr[p];
                    const __bf16* r0p = xsrc + (size_t)s0 * 128 + l8 * 16;
                    const bf16x8 a0 = *reinterpret_cast<const bf16x8*>(r0p);
                    const bf16x8 a1 = *reinterpret_cast<const bf16x8*>(r0p + 8);
#pragma unroll
                    for (int j = 0; j < 8; ++j) {
                        acc[j]     += (float)a0[j];
                        acc[8 + j] += (float)a1[j];
                    }
                }
                bf16x8 o0, o1;
#pragma unroll
                for (int j = 0; j < 8; ++j) { o0[j] = (__bf16)acc[j]; o1[j] = (__bf16)acc[8 + j]; }
                // swizzle at 16B-chunk granularity: chunk cb -> cb ^ (lr&7)
                char* base = (char*)atile + lr * 256;
                *reinterpret_cast<bf16x8*>(base + (((l8 * 2    ) << 4) ^ ((lr & 7) << 4))) = o0;
                *reinterpret_cast<bf16x8*>(base + (((l8 * 2 + 1) << 4) ^ ((lr & 7) << 4))) = o1;
            }
        }
        __syncthreads();   // atile ready, lsum zeroed

        f32x4 acc[2][8];
#pragma unroll
        for (int rf = 0; rf < 2; ++rf)
#pragma unroll
            for (int cf = 0; cf < 8; ++cf) {
                f32x4 z; z[0] = 0.f; z[1] = 0.f; z[2] = 0.f; z[3] = 0.f;
                acc[rf][cf] = z;
            }

        const __bf16* __restrict__ aggp = cg.agg[cj];
        const __bf16* __restrict__ Wp   = cg.Wp[cj];
#pragma unroll
        for (int ks = 0; ks < 8; ++ks) {
            const int koff = (ks & 3) * 32 + klane;
            bf16x8 a[2];
#pragma unroll
            for (int rf = 0; rf < 2; ++rf) {
                if (ks < 4) {
                    if (fused) {
                        const int lr = wv * 32 + rf * 16 + lrow;
                        const char* sp = (const char*)atile + lr * 256
                                       + ((koff * 2) ^ ((lr & 7) << 4));
                        a[rf] = *reinterpret_cast<const bf16x8*>(sp);
                    } else {
                        const bf16x8 av = *reinterpret_cast<const bf16x8*>(
                            aggp + (size_t)car[rf] * 128 + koff);
                        a[rf] = val[rf] ? av : z8;
                    }
                } else {
                    a[rf] = xd[rf][ks - 4];
                }
            }
            const bf16x8* wp8 = reinterpret_cast<const bf16x8*>(Wp) + (size_t)ks * 8 * 64 + lane;
            bf16x8 b[8];
#pragma unroll
            for (int cf = 0; cf < 8; ++cf) b[cf] = wp8[(size_t)cf * 64];
#pragma unroll
            for (int rf = 0; rf < 2; ++rf)
#pragma unroll
                for (int cf = 0; cf < 8; ++cf)
                    acc[rf][cf] = __builtin_amdgcn_mfma_f32_16x16x32_bf16(a[rf], b[cf], acc[rf][cf], 0, 0, 0);
        }

        const float* __restrict__ bias = cg.bias[cj];
        __bf16* __restrict__ hout = cg.hout[cj];
        float bc[8];
#pragma unroll
        for (int cf = 0; cf < 8; ++cf) bc[cf] = bias[cf * 16 + lrow];

        const int rb = (lane >> 4) * 4;
#pragma unroll
        for (int cf = 0; cf < 8; ++cf) {
            float s = 0.f, q = 0.f;
#pragma unroll
            for (int rf = 0; rf < 2; ++rf) {
#pragma unroll
                for (int rr = 0; rr < 4; ++rr) {
                    const int grow = r0 + wv * 32 + rf * 16 + rb + rr;
                    if (grow < M) {
                        const float hv = acc[rf][cf][rr] + bc[cf];
                        __builtin_nontemporal_store((__bf16)hv,
                            hout + (size_t)grow * 128 + cf * 16 + lrow);
                        s += hv; q += hv * hv;
                    }
                }
            }
            s += __shfl_xor(s, 16); s += __shfl_xor(s, 32);
            q += __shfl_xor(q, 16); q += __shfl_xor(q, 32);
            if (lane < 16) {
                atomicAdd(&lsum[cf * 16 + lane], s);
                atomicAdd(&lsq [cf * 16 + lane], q);
            }
        }
        __syncthreads();   // lsum complete; atile free for next conv
        float* __restrict__ st = cg.stats[cj];
        if (tid < 128) {
            atomicAdd(&st[tid],       lsum[tid]);
            atomicAdd(&st[128 + tid], lsq[tid]);
        }
    }
}

// ---------------------------------------------------------------- batched normalize + sum 3 convs
// out = base + sum_j gamma_j*(h_j-mu_j)*rsqrt(var_j+eps)+beta_j ; base = 0 (L0/bf16) or resid (L1/f32)
// h loads nontemporal: read-once stream, keep out of L2/L3.
template<bool F32OUT>
__global__ void __launch_bounds__(256) norm_group(NormGroup ng)
{
    __shared__ float ssc[3][128], ssh[3][128];
    const int tid = threadIdx.x;
    if (tid < 128) {
#pragma unroll
        for (int j = 0; j < 3; ++j) {
            const float mu   = ng.stats[j][tid] * ng.invM;
            const float var  = ng.stats[j][128 + tid] * ng.invM - mu * mu;
            const float scal = ng.gamma[j][tid] * rsqrtf(var + 1e-5f);
            ssc[j][tid] = scal;
            ssh[j][tid] = ng.beta[j][tid] - mu * scal;
        }
    }
    __syncthreads();

    const int t0   = blockIdx.x * 256 + tid;
    const int nthr = gridDim.x * 256;
    const int c0   = (t0 & 15) * 8;
    float sc[3][8], sh[3][8];
#pragma unroll
    for (int j = 0; j < 3; ++j)
#pragma unroll
        for (int k = 0; k < 8; ++k) { sc[j][k] = ssc[j][c0 + k]; sh[j][k] = ssh[j][c0 + k]; }

    const int nch = ng.M * 16;
    for (int ch = t0; ch < nch; ch += nthr) {
        float f[8] = {0.f, 0.f, 0.f, 0.f, 0.f, 0.f, 0.f, 0.f};
#pragma unroll
        for (int j = 0; j < 3; ++j) {
            const bf16x8 hv = __builtin_nontemporal_load(
                reinterpret_cast<const bf16x8*>(ng.h[j] + (size_t)ch * 8));
#pragma unroll
            for (int k = 0; k < 8; ++k) f[k] += (float)hv[k] * sc[j][k] + sh[j][k];
        }
        if constexpr (F32OUT) {
            const float* rp = ng.resid + (size_t)ch * 8;
            const float4 r0 = *reinterpret_cast<const float4*>(rp);
            const float4 r1 = *reinterpret_cast<const float4*>(rp + 4);
            float* op = (float*)ng.out + (size_t)ch * 8;
            float4 o0, o1;
            o0.x = r0.x + f[0]; o0.y = r0.y + f[1]; o0.z = r0.z + f[2]; o0.w = r0.w + f[3];
            o1.x = r1.x + f[4]; o1.y = r1.y + f[5]; o1.z = r1.z + f[6]; o1.w = r1.w + f[7];
            *reinterpret_cast<float4*>(op)     = o0;
            *reinterpret_cast<float4*>(op + 4) = o1;
        } else {
            bf16x8 ov;
#pragma unroll
            for (int k = 0; k < 8; ++k) ov[k] = (__bf16)f[k];
            *reinterpret_cast<bf16x8*>((__bf16*)ng.out + (size_t)ch * 8) = ov;
        }
    }
}

// ---------------------------------------------------------------- launch
extern "C" void kernel_launch(void* const* d_in, const int* in_sizes, int n_in,
                              void* d_out, int out_size, void* d_ws, size_t ws_size,
                              hipStream_t stream)
{
    const float* xin[3] = {(const float*)d_in[0], (const float*)d_in[1], (const float*)d_in[2]};
    const int N[3] = {in_sizes[0] / 128, in_sizes[1] / 128, in_sizes[2] / 128};
    const float* Wrel  = (const float*)d_in[12];
    const float* brel  = (const float*)d_in[13];
    const float* Wroot = (const float*)d_in[14];
    const float* gamma = (const float*)d_in[15];
    const float* beta  = (const float*)d_in[16];

    // ETS order: a2b b2a a2g g2a b2g g2b a2a b2b g2g  (atom=0,bond=1,global=2)
    const int cs[9] = {0, 1, 0, 2, 1, 2, 0, 1, 2};
    const int cd[9] = {1, 0, 2, 0, 2, 1, 0, 1, 2};
    // dst-groups: convs (ETS idx) per dst type
    const int gconv[3][3] = {{1, 3, 6},   // dst=atom : b2a, g2a, a2a
                             {0, 5, 7},   // dst=bond : a2b, g2b, b2b
                             {2, 4, 8}};  // dst=global: a2g, b2g, g2g

    const size_t nA = (size_t)N[0] * 128, nB = (size_t)N[1] * 128, nG = (size_t)N[2] * 128;
    const size_t off[3] = {0, nA, nA + nB};
    const size_t xtot = nA + nB + nG;
    size_t maxN = (size_t)N[0];
    if ((size_t)N[1] > maxN) maxN = N[1];
    if ((size_t)N[2] > maxN) maxN = N[2];

    // edge/bin geometry
    EdgeArgs ea;
    int Etot = 0, Nbins = 0;
    ea.ebase[0] = 0;
    for (int t = 0; t < 9; ++t) {
        ea.ei[t] = (const int*)d_in[3 + t];
        ea.E[t]  = in_sizes[3 + t] / 2;
        ea.ebase[t + 1] = ea.ebase[t] + ea.E[t];
        ea.binbase[t] = Nbins;
        Nbins += N[cd[t]];
    }
    Etot = ea.ebase[9];
    const int nb1 = (Nbins + SCHUNK - 1) / SCHUNK;

    // ws layout (~410 MB)
    auto al = [](size_t x) { return (x + 15) & ~(size_t)15; };
    char* w = (char*)d_ws;
    __bf16* x0b   = (__bf16*)w;  w += al(xtot * 2);
    __bf16* x1    = (__bf16*)w;  w += al(xtot * 2);
    __bf16* aggb  = (__bf16*)w;  w += al(2 * maxN * 128 * 2);
    __bf16* hbuf  = (__bf16*)w;  w += al(3 * maxN * 128 * 2);
    float*  stats = (float*)w;   w += al(18 * 256 * 4);
    __bf16* Wp    = (__bf16*)w;  w += al((size_t)18 * 32768 * 2);
    int*    deg   = (int*)w;     w += al((size_t)Nbins * 4);
    int*    rowptr= (int*)w;     w += al(((size_t)Nbins + 1) * 4);
    int*    cursor= (int*)w;     w += al((size_t)Nbins * 4);
    int*    csr   = (int*)w;     w += al((size_t)Etot * 4);
    int*    bsum  = (int*)w;     w += al((size_t)nb1 * 4);
    (void)ws_size; (void)n_in; (void)out_size;

    pack_w<<<288, 256, 0, stream>>>(Wrel, Wroot, Wp);
    for (int k = 0; k < 3; ++k) {
        const int n8 = (int)(((k == 0 ? nA : k == 1 ? nB : nG)) / 8);
        int cb = (n8 + 255) / 256; if (cb > 2048) cb = 2048;
        cvt_kernel<<<cb, 256, 0, stream>>>(xin[k], x0b + off[k], n8);
    }
    hipMemsetAsync(deg, 0, (size_t)Nbins * 4, stream);
    hipMemsetAsync(stats, 0, 18 * 256 * 4, stream);

    int eb = (Etot + 255) / 256; if (eb > 2048) eb = 2048;
    hist_kernel<<<eb, 256, 0, stream>>>(ea, Etot, deg);
    scan1_kernel<<<nb1, 256, 0, stream>>>(deg, Nbins, rowptr, bsum);
    scan2_kernel<<<1, 256, 0, stream>>>(bsum, nb1);
    int fb = (Nbins + 255) / 256; if (fb > 2048) fb = 2048;
    fixup_kernel<<<fb, 256, 0, stream>>>(rowptr, bsum, Nbins, Etot, cursor);
    place_kernel<<<2048, 256, 0, stream>>>(ea, Etot, Nbins, cursor, csr);

    float* dout = (float*)d_out;

    for (int L = 0; L < 2; ++L) {
        const __bf16* xb = (L == 0) ? x0b : x1;

        // pre-gather high-degree (deg>=8) convs: a2g (ets 2), b2g (ets 4)
        {
            const int Ng = N[2];
            int gb2 = (Ng * 64 + 255) / 256; if (gb2 > 2048) gb2 = 2048; if (gb2 < 1) gb2 = 1;
            gather64<<<gb2, 256, 0, stream>>>(xb + off[0], rowptr + ea.binbase[2], csr,
                                              aggb, Ng);
            gather64<<<gb2, 256, 0, stream>>>(xb + off[1], rowptr + ea.binbase[4], csr,
                                              aggb + maxN * 128, Ng);
        }

        for (int g = 0; g < 3; ++g) {
            const int d  = g;           // dst type == group index
            const int Nd = N[d];
            ConvGroup cg;
            NormGroup ng;
            cg.xdst = xb + off[d];
            cg.csr  = csr;
            cg.M    = Nd;
            for (int j = 0; j < 3; ++j) {
                const int et = gconv[g][j];
                const int li = L * 9 + et;
                cg.rowptr[j] = rowptr + ea.binbase[et];
                cg.xsrc[j]   = xb + off[cs[et]];
                cg.Wp[j]     = Wp + (size_t)li * 32768;
                cg.bias[j]   = brel + li * 128;
                cg.stats[j]  = stats + li * 256;
                cg.hout[j]   = hbuf + (size_t)j * maxN * 128;
                const bool hi = (et == 2) || (et == 4);
                cg.fused[j]  = hi ? 0 : 1;
                cg.agg[j]    = (et == 2) ? aggb : (et == 4 ? aggb + maxN * 128 : (const __bf16*)nullptr);
                ng.h[j]      = cg.hout[j];
                ng.stats[j]  = cg.stats[j];
                ng.gamma[j]  = gamma + li * 128;
                ng.beta[j]   = beta + li * 128;
            }
            const int gb = (Nd + 127) / 128;
            fgemm_group<<<gb, 256, 0, stream>>>(cg);

            ng.invM = 1.0f / (float)Nd;
            ng.M    = Nd;
            const long long nch = (long long)Nd * 16;
            int nb = (int)((nch + 255) / 256); if (nb > 2048) nb = 2048;
            if (L == 0) {
                ng.resid = nullptr;
                ng.out   = (void*)(x1 + off[d]);
                norm_group<false><<<nb, 256, 0, stream>>>(ng);
            } else {
                ng.resid = xin[d];
                ng.out   = (void*)(dout + off[d]);
                norm_group<true><<<nb, 256, 0, stream>>>(ng);
            }
        }
    }
}

// Round 15
// 1460.349 us; speedup vs baseline: 1.3242x; 1.3242x over previous
//
#include <hip/hip_runtime.h>
#include <hip/hip_bf16.h>

typedef __bf16 bf16x8 __attribute__((ext_vector_type(8)));
typedef float  f32x4  __attribute__((ext_vector_type(4)));

#define SCHUNK 2048  // elements per scan1 block (256 thr * 8)

struct EdgeArgs {
    const int* ei[9];
    int E[9];
    int ebase[10];   // prefix over edges
    int binbase[9];  // prefix over dst bins
};

struct ConvGroup {          // 3 convs sharing the same dst type
    const int* rowptr[3];
    const __bf16* xsrc[3];
    const __bf16* agg[3];   // pre-gathered A (unfused convs)
    const __bf16* Wp[3];
    const float* bias[3];
    float* stats[3];
    __bf16* hout[3];
    const __bf16* xdst;
    const int* csr;
    int fused[3];
    int M;
};

struct NormGroup {
    const __bf16* h[3];
    const float* stats[3];
    const float* gamma[3];
    const float* beta[3];
    const float* resid;     // f32 base (L1) or null
    void* out;
    float invM;
    int M;
};

// ---------------------------------------------------------------- pack W
// Layout: [li=L*9+i][ks(8)][cf(8)][lane(64)][j(8)]  (bf16)
// k = ks*32 + (lane>>4)*8 + j ; col = cf*16 + (lane&15)
__global__ void __launch_bounds__(256) pack_w(const float* __restrict__ Wrel,
                                              const float* __restrict__ Wroot,
                                              __bf16* __restrict__ Wp)
{
    const int idx = blockIdx.x * 256 + threadIdx.x;
    if (idx >= 2 * 9 * 8 * 8 * 64) return;
    const int lane = idx & 63;
    int t = idx >> 6;
    const int cf = t & 7; t >>= 3;
    const int ks = t & 7; t >>= 3;
    const int li = t;  // 0..17
    const int col = cf * 16 + (lane & 15);
    const int kb  = ks * 32 + (lane >> 4) * 8;
    bf16x8 o;
#pragma unroll
    for (int j = 0; j < 8; ++j) {
        const int k = kb + j;
        const float v = (k < 128)
            ? Wrel [((size_t)li * 128 + k)        * 128 + col]
            : Wroot[((size_t)li * 128 + (k - 128)) * 128 + col];
        o[j] = (__bf16)v;
    }
    *reinterpret_cast<bf16x8*>(Wp + (size_t)idx * 8) = o;
}

// ---------------------------------------------------------------- f32 -> bf16 convert
__global__ void __launch_bounds__(256) cvt_kernel(const float* __restrict__ in,
                                                  __bf16* __restrict__ out, int n8)
{
    int i = blockIdx.x * 256 + threadIdx.x;
    const int stride = gridDim.x * 256;
    for (; i < n8; i += stride) {
        const float4 f0 = *reinterpret_cast<const float4*>(in + (size_t)i * 8);
        const float4 f1 = *reinterpret_cast<const float4*>(in + (size_t)i * 8 + 4);
        bf16x8 o;
        o[0] = (__bf16)f0.x; o[1] = (__bf16)f0.y; o[2] = (__bf16)f0.z; o[3] = (__bf16)f0.w;
        o[4] = (__bf16)f1.x; o[5] = (__bf16)f1.y; o[6] = (__bf16)f1.z; o[7] = (__bf16)f1.w;
        *reinterpret_cast<bf16x8*>(out + (size_t)i * 8) = o;
    }
}

// ---------------------------------------------------------------- CSR build
__global__ void __launch_bounds__(256) hist_kernel(EdgeArgs ea, int Etot,
                                                   int* __restrict__ deg)
{
    int g = blockIdx.x * 256 + threadIdx.x;
    const int stride = gridDim.x * 256;
    for (; g < Etot; g += stride) {
        int t = 0;
        while (g >= ea.ebase[t + 1]) ++t;
        const int e = g - ea.ebase[t];
        const int dst = __builtin_nontemporal_load(&ea.ei[t][ea.E[t] + e]);
        atomicAdd(&deg[ea.binbase[t] + dst], 1);
    }
}

__global__ void __launch_bounds__(256) scan1_kernel(const int* __restrict__ deg, int n,
                                                    int* __restrict__ rowptr,
                                                    int* __restrict__ bsum)
{
    __shared__ int lds[256];
    const int tid = threadIdx.x;
    const int base = blockIdx.x * SCHUNK + tid * 8;
    int v[8]; int tsum = 0;
#pragma unroll
    for (int j = 0; j < 8; ++j) { v[j] = (base + j < n) ? deg[base + j] : 0; tsum += v[j]; }
    int incl = tsum;
    lds[tid] = incl; __syncthreads();
    for (int off = 1; off < 256; off <<= 1) {
        const int add = (tid >= off) ? lds[tid - off] : 0;
        __syncthreads();
        incl += add; lds[tid] = incl; __syncthreads();
    }
    if (tid == 255) bsum[blockIdx.x] = incl;
    int run = incl - tsum;
#pragma unroll
    for (int j = 0; j < 8; ++j) { if (base + j < n) rowptr[base + j] = run; run += v[j]; }
}

__global__ void __launch_bounds__(256) scan2_kernel(int* __restrict__ bsum, int nb)
{
    __shared__ int lds[256];
    __shared__ int carry_s;
    const int tid = threadIdx.x;
    if (tid == 0) carry_s = 0;
    __syncthreads();
    for (int base = 0; base < nb; base += 256) {
        const int v = (base + tid < nb) ? bsum[base + tid] : 0;
        int incl = v;
        lds[tid] = incl; __syncthreads();
        for (int off = 1; off < 256; off <<= 1) {
            const int add = (tid >= off) ? lds[tid - off] : 0;
            __syncthreads();
            incl += add; lds[tid] = incl; __syncthreads();
        }
        const int total = lds[255];
        const int carry = carry_s;
        if (base + tid < nb) bsum[base + tid] = incl - v + carry;
        __syncthreads();
        if (tid == 0) carry_s = carry + total;
        __syncthreads();
    }
}

__global__ void __launch_bounds__(256) fixup_kernel(int* __restrict__ rowptr,
                                                    const int* __restrict__ bsum, int n,
                                                    int Etot, int* __restrict__ cursor)
{
    int i = blockIdx.x * 256 + threadIdx.x;
    const int stride = gridDim.x * 256;
    if (i == 0) rowptr[n] = Etot;
    for (; i < n; i += stride) {
        const int r = rowptr[i] + bsum[i >> 11];
        rowptr[i] = r; cursor[i] = r;
    }
}

// XCD-sharded placement; nontemporal edge reads keep the streaming re-read from
// evicting the shard's dirty cursor/csr lines out of L2.
__global__ void __launch_bounds__(256) place_kernel(EdgeArgs ea, int Etot, int Nbins,
                                                    int* __restrict__ cursor,
                                                    int* __restrict__ csr)
{
    const int shard = blockIdx.x & 7;
    const int lo = (int)(((long long)shard * Nbins) >> 3);
    const int hi = (int)(((long long)(shard + 1) * Nbins) >> 3);
    int g = (blockIdx.x >> 3) * 256 + threadIdx.x;
    const int stride = (gridDim.x >> 3) * 256;
    for (; g < Etot; g += stride) {
        int t = 0;
        while (g >= ea.ebase[t + 1]) ++t;
        const int e = g - ea.ebase[t];
        const int dst = __builtin_nontemporal_load(&ea.ei[t][ea.E[t] + e]);
        const int gb = ea.binbase[t] + dst;
        if (gb >= lo && gb < hi) {
            const int src = __builtin_nontemporal_load(&ea.ei[t][e]);
            const int pos = atomicAdd(&cursor[gb], 1);
            csr[pos] = src;
        }
    }
}

// ---------------------------------------------------------------- gather64
// wave per dst row (high-degree rows, dst=global): pairwise loads, 8 in flight/wave.
__global__ void __launch_bounds__(256) gather64(const __bf16* __restrict__ x,
                                                const int* __restrict__ rowptr,
                                                const int* __restrict__ csr,
                                                __bf16* __restrict__ agg, int N)
{
    const int lane = threadIdx.x & 63;
    const int l16 = lane & 15, grp = lane >> 4;
    int wv = (blockIdx.x * 256 + threadIdx.x) >> 6;
    const int nwv = (gridDim.x * 256) >> 6;
    for (int row = wv; row < N; row += nwv) {
        const int p0 = rowptr[row], p1 = rowptr[row + 1];
        float acc[8] = {0.f, 0.f, 0.f, 0.f, 0.f, 0.f, 0.f, 0.f};
        int p = p0 + grp * 2;
        for (; p + 2 <= p1; p += 8) {
            const int s0 = csr[p], s1 = csr[p + 1];
            const bf16x8 v0 = *reinterpret_cast<const bf16x8*>(x + (size_t)s0 * 128 + l16 * 8);
            const bf16x8 v1 = *reinterpret_cast<const bf16x8*>(x + (size_t)s1 * 128 + l16 * 8);
#pragma unroll
            for (int j = 0; j < 8; ++j) acc[j] += (float)v0[j] + (float)v1[j];
        }
        if (p < p1) {
            const int s0 = csr[p];
            const bf16x8 v0 = *reinterpret_cast<const bf16x8*>(x + (size_t)s0 * 128 + l16 * 8);
#pragma unroll
            for (int j = 0; j < 8; ++j) acc[j] += (float)v0[j];
        }
#pragma unroll
        for (int j = 0; j < 8; ++j) {
            acc[j] += __shfl_xor(acc[j], 16);
            acc[j] += __shfl_xor(acc[j], 32);
        }
        if (grp == 0) {
            bf16x8 o;
#pragma unroll
            for (int j = 0; j < 8; ++j) o[j] = (__bf16)acc[j];
            *reinterpret_cast<bf16x8*>(agg + (size_t)row * 128 + l16 * 8) = o;
        }
    }
}

// ---------------------------------------------------------------- batched fused gather+GEMM+stats
// EXACT R12 structure (dim3(gb,3) grid, 8-lane gather groups, 32 chains/block,
// 4 rows/chain, (256,3)). Single delta: the epilogue stages h into the now-free
// atile (swizzled bf16), then NT-stores full 64B+ lines (wave writes 1KB
// contiguous). R14's per-element NT stores wrote 32B fragments -> 2x write
// amplification (WRITE 181->332MB); this keeps h out of L2/L3 WITHOUT the
// amplification, so the random-gather x working set stays L3-resident.
__global__ void __launch_bounds__(256, 3) fgemm_group(ConvGroup cg)
{
    __shared__ __bf16 atile[128 * 128];   // 32 KB; A-tile, then h staging
    __shared__ float lsum[128];
    __shared__ float lsq[128];
    const int cj   = blockIdx.y;
    const int M    = cg.M;
    const int tid  = threadIdx.x;
    const int lane = tid & 63;
    const int wv   = tid >> 6;
    if (tid < 128) { lsum[tid] = 0.f; lsq[tid] = 0.f; }

    const int r0 = blockIdx.x * 128;
    const int lrow  = lane & 15;
    const int klane = (lane >> 4) * 8;

    int  car[2]; bool val[2];
#pragma unroll
    for (int rf = 0; rf < 2; ++rf) {
        const int ar = r0 + wv * 32 + rf * 16 + lrow;
        val[rf] = ar < M;
        car[rf] = val[rf] ? ar : (M - 1);
    }
    bf16x8 z8;
#pragma unroll
    for (int j = 0; j < 8; ++j) z8[j] = (__bf16)0.f;

    // early xdst fragment loads (k=128..255 half of A) — overlap with gather
    bf16x8 xd[2][4];
#pragma unroll
    for (int rf = 0; rf < 2; ++rf)
#pragma unroll
        for (int kk = 0; kk < 4; ++kk) {
            const bf16x8 av = *reinterpret_cast<const bf16x8*>(
                cg.xdst + (size_t)car[rf] * 128 + kk * 32 + klane);
            xd[rf][kk] = val[rf] ? av : z8;
        }

    const bool fused = cg.fused[cj] != 0;
    if (fused) {
        const int* __restrict__ rp  = cg.rowptr[cj];
        const int* __restrict__ csr = cg.csr;
        const __bf16* __restrict__ xsrc = cg.xsrc[cj];
        const int grp = tid >> 3, l8 = tid & 7;   // 32 groups of 8 lanes
        int pr[5];
#pragma unroll
        for (int rr = 0; rr < 5; ++rr) {
            int rw = r0 + grp * 4 + rr;
            pr[rr] = rp[rw > M ? M : rw];   // rows >= M collapse to empty ranges
        }
#pragma unroll
        for (int rr = 0; rr < 4; ++rr) {
            const int lr = grp * 4 + rr;
            const int p1 = pr[rr + 1];
            float acc[16];
#pragma unroll
            for (int j = 0; j < 16; ++j) acc[j] = 0.f;
            int p = pr[rr];
            for (; p + 2 <= p1; p += 2) {   // pairwise: 2 csr + 4 row loads in flight
                const int s0 = csr[p], s1 = csr[p + 1];
                const __bf16* r0p = xsrc + (size_t)s0 * 128 + l8 * 16;
                const __bf16* r1p = xsrc + (size_t)s1 * 128 + l8 * 16;
                const bf16x8 a0 = *reinterpret_cast<const bf16x8*>(r0p);
                const bf16x8 a1 = *reinterpret_cast<const bf16x8*>(r0p + 8);
                const bf16x8 b0 = *reinterpret_cast<const bf16x8*>(r1p);
                const bf16x8 b1 = *reinterpret_cast<const bf16x8*>(r1p + 8);
#pragma unroll
                for (int j = 0; j < 8; ++j) {
                    acc[j]     += (float)a0[j] + (float)b0[j];
                    acc[8 + j] += (float)a1[j] + (float)b1[j];
                }
            }
            if (p < p1) {
                const int s0 = csr[p];
                const __bf16* r0p = xsrc + (size_t)s0 * 128 + l8 * 16;
                const bf16x8 a0 = *reinterpret_cast<const bf16x8*>(r0p);
                const bf16x8 a1 = *reinterpret_cast<const bf16x8*>(r0p + 8);
#pragma unroll
                for (int j = 0; j < 8; ++j) {
                    acc[j]     += (float)a0[j];
                    acc[8 + j] += (float)a1[j];
                }
            }
            bf16x8 o0, o1;
#pragma unroll
            for (int j = 0; j < 8; ++j) { o0[j] = (__bf16)acc[j]; o1[j] = (__bf16)acc[8 + j]; }
            // swizzle at 16B-chunk granularity: chunk cb -> cb ^ (lr&7)
            char* base = (char*)atile + lr * 256;
            *reinterpret_cast<bf16x8*>(base + (((l8 * 2    ) << 4) ^ ((lr & 7) << 4))) = o0;
            *reinterpret_cast<bf16x8*>(base + (((l8 * 2 + 1) << 4) ^ ((lr & 7) << 4))) = o1;
        }
    }
    __syncthreads();

    f32x4 acc[2][8];
#pragma unroll
    for (int rf = 0; rf < 2; ++rf)
#pragma unroll
        for (int cf = 0; cf < 8; ++cf) {
            f32x4 z; z[0] = 0.f; z[1] = 0.f; z[2] = 0.f; z[3] = 0.f;
            acc[rf][cf] = z;
        }

    const __bf16* __restrict__ aggp = cg.agg[cj];
    const __bf16* __restrict__ Wp   = cg.Wp[cj];
#pragma unroll
    for (int ks = 0; ks < 8; ++ks) {
        const int koff = (ks & 3) * 32 + klane;
        bf16x8 a[2];
#pragma unroll
        for (int rf = 0; rf < 2; ++rf) {
            if (ks < 4) {
                if (fused) {
                    const int lr = wv * 32 + rf * 16 + lrow;
                    const char* sp = (const char*)atile + lr * 256
                                   + ((koff * 2) ^ ((lr & 7) << 4));
                    a[rf] = *reinterpret_cast<const bf16x8*>(sp);
                } else {
                    const bf16x8 av = *reinterpret_cast<const bf16x8*>(
                        aggp + (size_t)car[rf] * 128 + koff);
                    a[rf] = val[rf] ? av : z8;
                }
            } else {
                a[rf] = xd[rf][ks - 4];
            }
        }
        const bf16x8* wp8 = reinterpret_cast<const bf16x8*>(Wp) + (size_t)ks * 8 * 64 + lane;
        bf16x8 b[8];
#pragma unroll
        for (int cf = 0; cf < 8; ++cf) b[cf] = wp8[(size_t)cf * 64];
#pragma unroll
        for (int rf = 0; rf < 2; ++rf)
#pragma unroll
            for (int cf = 0; cf < 8; ++cf)
                acc[rf][cf] = __builtin_amdgcn_mfma_f32_16x16x32_bf16(a[rf], b[cf], acc[rf][cf], 0, 0, 0);
    }

    __syncthreads();   // all atile A reads done; safe to overwrite with h

    const float* __restrict__ bias = cg.bias[cj];
    __bf16* __restrict__ hout = cg.hout[cj];
    float bc[8];
#pragma unroll
    for (int cf = 0; cf < 8; ++cf) bc[cf] = bias[cf * 16 + lrow];

    const int rb = (lane >> 4) * 4;
#pragma unroll
    for (int cf = 0; cf < 8; ++cf) {
        float s = 0.f, q = 0.f;
#pragma unroll
        for (int rf = 0; rf < 2; ++rf) {
#pragma unroll
            for (int rr = 0; rr < 4; ++rr) {
                const int lr = wv * 32 + rf * 16 + rb + rr;
                const float hv = acc[rf][cf][rr] + bc[cf];
                // stage h into atile (swizzled): logical byte = cf*32 + lrow*2
                *reinterpret_cast<__bf16*>((char*)atile + lr * 256 +
                    ((cf * 32 + lrow * 2) ^ ((lr & 7) << 4))) = (__bf16)hv;
                if (r0 + lr < M) { s += hv; q += hv * hv; }
            }
        }
        s += __shfl_xor(s, 16); s += __shfl_xor(s, 32);
        q += __shfl_xor(q, 16); q += __shfl_xor(q, 32);
        if (lane < 16) {
            atomicAdd(&lsum[cf * 16 + lane], s);
            atomicAdd(&lsq [cf * 16 + lane], q);
        }
    }
    __syncthreads();   // h tile staged; lsum complete

    // NT writeback: wave writes 1KB contiguous (16 lanes x 16B = 256B per row-chunk run)
    for (int i = tid; i < 128 * 16; i += 256) {
        const int row = i >> 4, ch = i & 15;
        const int grow = r0 + row;
        if (grow < M) {
            const bf16x8 v = *reinterpret_cast<const bf16x8*>(
                (const char*)atile + row * 256 + ((ch * 16) ^ ((row & 7) << 4)));
            __builtin_nontemporal_store(v,
                reinterpret_cast<bf16x8*>(hout + (size_t)grow * 128 + ch * 8));
        }
    }

    float* __restrict__ st = cg.stats[cj];
    if (tid < 128) {
        atomicAdd(&st[tid],       lsum[tid]);
        atomicAdd(&st[128 + tid], lsq[tid]);
    }
}

// ---------------------------------------------------------------- batched normalize + sum 3 convs
// out = base + sum_j gamma_j*(h_j-mu_j)*rsqrt(var_j+eps)+beta_j ; base = 0 (L0/bf16) or resid (L1/f32)
// h loads nontemporal: read-once stream, keep out of L2/L3.
template<bool F32OUT>
__global__ void __launch_bounds__(256) norm_group(NormGroup ng)
{
    __shared__ float ssc[3][128], ssh[3][128];
    const int tid = threadIdx.x;
    if (tid < 128) {
#pragma unroll
        for (int j = 0; j < 3; ++j) {
            const float mu   = ng.stats[j][tid] * ng.invM;
            const float var  = ng.stats[j][128 + tid] * ng.invM - mu * mu;
            const float scal = ng.gamma[j][tid] * rsqrtf(var + 1e-5f);
            ssc[j][tid] = scal;
            ssh[j][tid] = ng.beta[j][tid] - mu * scal;
        }
    }
    __syncthreads();

    const int t0   = blockIdx.x * 256 + tid;
    const int nthr = gridDim.x * 256;
    const int c0   = (t0 & 15) * 8;
    float sc[3][8], sh[3][8];
#pragma unroll
    for (int j = 0; j < 3; ++j)
#pragma unroll
        for (int k = 0; k < 8; ++k) { sc[j][k] = ssc[j][c0 + k]; sh[j][k] = ssh[j][c0 + k]; }

    const int nch = ng.M * 16;
    for (int ch = t0; ch < nch; ch += nthr) {
        float f[8] = {0.f, 0.f, 0.f, 0.f, 0.f, 0.f, 0.f, 0.f};
#pragma unroll
        for (int j = 0; j < 3; ++j) {
            const bf16x8 hv = __builtin_nontemporal_load(
                reinterpret_cast<const bf16x8*>(ng.h[j] + (size_t)ch * 8));
#pragma unroll
            for (int k = 0; k < 8; ++k) f[k] += (float)hv[k] * sc[j][k] + sh[j][k];
        }
        if constexpr (F32OUT) {
            const float* rp = ng.resid + (size_t)ch * 8;
            const float4 r0 = *reinterpret_cast<const float4*>(rp);
            const float4 r1 = *reinterpret_cast<const float4*>(rp + 4);
            float* op = (float*)ng.out + (size_t)ch * 8;
            float4 o0, o1;
            o0.x = r0.x + f[0]; o0.y = r0.y + f[1]; o0.z = r0.z + f[2]; o0.w = r0.w + f[3];
            o1.x = r1.x + f[4]; o1.y = r1.y + f[5]; o1.z = r1.z + f[6]; o1.w = r1.w + f[7];
            *reinterpret_cast<float4*>(op)     = o0;
            *reinterpret_cast<float4*>(op + 4) = o1;
        } else {
            bf16x8 ov;
#pragma unroll
            for (int k = 0; k < 8; ++k) ov[k] = (__bf16)f[k];
            *reinterpret_cast<bf16x8*>((__bf16*)ng.out + (size_t)ch * 8) = ov;
        }
    }
}

// ---------------------------------------------------------------- launch
extern "C" void kernel_launch(void* const* d_in, const int* in_sizes, int n_in,
                              void* d_out, int out_size, void* d_ws, size_t ws_size,
                              hipStream_t stream)
{
    const float* xin[3] = {(const float*)d_in[0], (const float*)d_in[1], (const float*)d_in[2]};
    const int N[3] = {in_sizes[0] / 128, in_sizes[1] / 128, in_sizes[2] / 128};
    const float* Wrel  = (const float*)d_in[12];
    const float* brel  = (const float*)d_in[13];
    const float* Wroot = (const float*)d_in[14];
    const float* gamma = (const float*)d_in[15];
    const float* beta  = (const float*)d_in[16];

    // ETS order: a2b b2a a2g g2a b2g g2b a2a b2b g2g  (atom=0,bond=1,global=2)
    const int cs[9] = {0, 1, 0, 2, 1, 2, 0, 1, 2};
    const int cd[9] = {1, 0, 2, 0, 2, 1, 0, 1, 2};
    // dst-groups: convs (ETS idx) per dst type
    const int gconv[3][3] = {{1, 3, 6},   // dst=atom : b2a, g2a, a2a
                             {0, 5, 7},   // dst=bond : a2b, g2b, b2b
                             {2, 4, 8}};  // dst=global: a2g, b2g, g2g

    const size_t nA = (size_t)N[0] * 128, nB = (size_t)N[1] * 128, nG = (size_t)N[2] * 128;
    const size_t off[3] = {0, nA, nA + nB};
    const size_t xtot = nA + nB + nG;
    size_t maxN = (size_t)N[0];
    if ((size_t)N[1] > maxN) maxN = N[1];
    if ((size_t)N[2] > maxN) maxN = N[2];

    // edge/bin geometry
    EdgeArgs ea;
    int Etot = 0, Nbins = 0;
    ea.ebase[0] = 0;
    for (int t = 0; t < 9; ++t) {
        ea.ei[t] = (const int*)d_in[3 + t];
        ea.E[t]  = in_sizes[3 + t] / 2;
        ea.ebase[t + 1] = ea.ebase[t] + ea.E[t];
        ea.binbase[t] = Nbins;
        Nbins += N[cd[t]];
    }
    Etot = ea.ebase[9];
    const int nb1 = (Nbins + SCHUNK - 1) / SCHUNK;

    // ws layout (~410 MB)
    auto al = [](size_t x) { return (x + 15) & ~(size_t)15; };
    char* w = (char*)d_ws;
    __bf16* x0b   = (__bf16*)w;  w += al(xtot * 2);
    __bf16* x1    = (__bf16*)w;  w += al(xtot * 2);
    __bf16* aggb  = (__bf16*)w;  w += al(2 * maxN * 128 * 2);
    __bf16* hbuf  = (__bf16*)w;  w += al(3 * maxN * 128 * 2);
    float*  stats = (float*)w;   w += al(18 * 256 * 4);
    __bf16* Wp    = (__bf16*)w;  w += al((size_t)18 * 32768 * 2);
    int*    deg   = (int*)w;     w += al((size_t)Nbins * 4);
    int*    rowptr= (int*)w;     w += al(((size_t)Nbins + 1) * 4);
    int*    cursor= (int*)w;     w += al((size_t)Nbins * 4);
    int*    csr   = (int*)w;     w += al((size_t)Etot * 4);
    int*    bsum  = (int*)w;     w += al((size_t)nb1 * 4);
    (void)ws_size; (void)n_in; (void)out_size;

    pack_w<<<288, 256, 0, stream>>>(Wrel, Wroot, Wp);
    for (int k = 0; k < 3; ++k) {
        const int n8 = (int)(((k == 0 ? nA : k == 1 ? nB : nG)) / 8);
        int cb = (n8 + 255) / 256; if (cb > 2048) cb = 2048;
        cvt_kernel<<<cb, 256, 0, stream>>>(xin[k], x0b + off[k], n8);
    }
    hipMemsetAsync(deg, 0, (size_t)Nbins * 4, stream);
    hipMemsetAsync(stats, 0, 18 * 256 * 4, stream);

    int eb = (Etot + 255) / 256; if (eb > 2048) eb = 2048;
    hist_kernel<<<eb, 256, 0, stream>>>(ea, Etot, deg);
    scan1_kernel<<<nb1, 256, 0, stream>>>(deg, Nbins, rowptr, bsum);
    scan2_kernel<<<1, 256, 0, stream>>>(bsum, nb1);
    int fb = (Nbins + 255) / 256; if (fb > 2048) fb = 2048;
    fixup_kernel<<<fb, 256, 0, stream>>>(rowptr, bsum, Nbins, Etot, cursor);
    place_kernel<<<2048, 256, 0, stream>>>(ea, Etot, Nbins, cursor, csr);

    float* dout = (float*)d_out;

    for (int L = 0; L < 2; ++L) {
        const __bf16* xb = (L == 0) ? x0b : x1;

        // pre-gather high-degree (deg>=8) convs: a2g (ets 2), b2g (ets 4)
        {
            const int Ng = N[2];
            int gb2 = (Ng * 64 + 255) / 256; if (gb2 > 2048) gb2 = 2048; if (gb2 < 1) gb2 = 1;
            gather64<<<gb2, 256, 0, stream>>>(xb + off[0], rowptr + ea.binbase[2], csr,
                                              aggb, Ng);
            gather64<<<gb2, 256, 0, stream>>>(xb + off[1], rowptr + ea.binbase[4], csr,
                                              aggb + maxN * 128, Ng);
        }

        for (int g = 0; g < 3; ++g) {
            const int d  = g;           // dst type == group index
            const int Nd = N[d];
            ConvGroup cg;
            NormGroup ng;
            cg.xdst = xb + off[d];
            cg.csr  = csr;
            cg.M    = Nd;
            for (int j = 0; j < 3; ++j) {
                const int et = gconv[g][j];
                const int li = L * 9 + et;
                cg.rowptr[j] = rowptr + ea.binbase[et];
                cg.xsrc[j]   = xb + off[cs[et]];
                cg.Wp[j]     = Wp + (size_t)li * 32768;
                cg.bias[j]   = brel + li * 128;
                cg.stats[j]  = stats + li * 256;
                cg.hout[j]   = hbuf + (size_t)j * maxN * 128;
                const bool hi = (et == 2) || (et == 4);
                cg.fused[j]  = hi ? 0 : 1;
                cg.agg[j]    = (et == 2) ? aggb : (et == 4 ? aggb + maxN * 128 : (const __bf16*)nullptr);
                ng.h[j]      = cg.hout[j];
                ng.stats[j]  = cg.stats[j];
                ng.gamma[j]  = gamma + li * 128;
                ng.beta[j]   = beta + li * 128;
            }
            const int gb = (Nd + 127) / 128;
            fgemm_group<<<dim3(gb, 3), 256, 0, stream>>>(cg);

            ng.invM = 1.0f / (float)Nd;
            ng.M    = Nd;
            const long long nch = (long long)Nd * 16;
            int nb = (int)((nch + 255) / 256); if (nb > 2048) nb = 2048;
            if (L == 0) {
                ng.resid = nullptr;
                ng.out   = (void*)(x1 + off[d]);
                norm_group<false><<<nb, 256, 0, stream>>>(ng);
            } else {
                ng.resid = xin[d];
                ng.out   = (void*)(dout + off[d]);
                norm_group<true><<<nb, 256, 0, stream>>>(ng);
            }
        }
    }
}

// Round 16
// 1412.065 us; speedup vs baseline: 1.3695x; 1.0342x over previous
//
#include <hip/hip_runtime.h>
#include <hip/hip_bf16.h>

typedef __bf16 bf16x8 __attribute__((ext_vector_type(8)));
typedef float  f32x4  __attribute__((ext_vector_type(4)));

#define SCHUNK 2048  // elements per scan1 block (256 thr * 8)

struct EdgeArgs {
    const int* ei[9];
    int E[9];
    int ebase[10];   // prefix over edges
    int binbase[9];  // prefix over dst bins
};

struct ConvGroup {          // 3 convs sharing the same dst type
    const int* rowptr[3];
    const __bf16* xsrc[3];
    const __bf16* agg[3];   // pre-gathered A (unfused convs)
    const __bf16* Wp[3];
    const float* bias[3];
    float* stats[3];
    __bf16* hout[3];
    const __bf16* xdst;
    const int* csr;
    int fused[3];
    int M;
};

struct NormGroup {
    const __bf16* h[3];
    const float* stats[3];
    const float* gamma[3];
    const float* beta[3];
    const float* resid;     // f32 base (L1) or null
    void* out;
    float invM;
    int M;
};

// ---------------------------------------------------------------- pack W
// Layout: [li=L*9+i][ks(8)][cf(8)][lane(64)][j(8)]  (bf16)
// k = ks*32 + (lane>>4)*8 + j ; col = cf*16 + (lane&15)
__global__ void __launch_bounds__(256) pack_w(const float* __restrict__ Wrel,
                                              const float* __restrict__ Wroot,
                                              __bf16* __restrict__ Wp)
{
    const int idx = blockIdx.x * 256 + threadIdx.x;
    if (idx >= 2 * 9 * 8 * 8 * 64) return;
    const int lane = idx & 63;
    int t = idx >> 6;
    const int cf = t & 7; t >>= 3;
    const int ks = t & 7; t >>= 3;
    const int li = t;  // 0..17
    const int col = cf * 16 + (lane & 15);
    const int kb  = ks * 32 + (lane >> 4) * 8;
    bf16x8 o;
#pragma unroll
    for (int j = 0; j < 8; ++j) {
        const int k = kb + j;
        const float v = (k < 128)
            ? Wrel [((size_t)li * 128 + k)        * 128 + col]
            : Wroot[((size_t)li * 128 + (k - 128)) * 128 + col];
        o[j] = (__bf16)v;
    }
    *reinterpret_cast<bf16x8*>(Wp + (size_t)idx * 8) = o;
}

// ---------------------------------------------------------------- f32 -> bf16 convert
__global__ void __launch_bounds__(256) cvt_kernel(const float* __restrict__ in,
                                                  __bf16* __restrict__ out, int n8)
{
    int i = blockIdx.x * 256 + threadIdx.x;
    const int stride = gridDim.x * 256;
    for (; i < n8; i += stride) {
        const float4 f0 = *reinterpret_cast<const float4*>(in + (size_t)i * 8);
        const float4 f1 = *reinterpret_cast<const float4*>(in + (size_t)i * 8 + 4);
        bf16x8 o;
        o[0] = (__bf16)f0.x; o[1] = (__bf16)f0.y; o[2] = (__bf16)f0.z; o[3] = (__bf16)f0.w;
        o[4] = (__bf16)f1.x; o[5] = (__bf16)f1.y; o[6] = (__bf16)f1.z; o[7] = (__bf16)f1.w;
        *reinterpret_cast<bf16x8*>(out + (size_t)i * 8) = o;
    }
}

// ---------------------------------------------------------------- CSR build
__global__ void __launch_bounds__(256) hist_kernel(EdgeArgs ea, int Etot,
                                                   int* __restrict__ deg)
{
    int g = blockIdx.x * 256 + threadIdx.x;
    const int stride = gridDim.x * 256;
    for (; g < Etot; g += stride) {
        int t = 0;
        while (g >= ea.ebase[t + 1]) ++t;
        const int e = g - ea.ebase[t];
        const int dst = __builtin_nontemporal_load(&ea.ei[t][ea.E[t] + e]);
        atomicAdd(&deg[ea.binbase[t] + dst], 1);
    }
}

__global__ void __launch_bounds__(256) scan1_kernel(const int* __restrict__ deg, int n,
                                                    int* __restrict__ rowptr,
                                                    int* __restrict__ bsum)
{
    __shared__ int lds[256];
    const int tid = threadIdx.x;
    const int base = blockIdx.x * SCHUNK + tid * 8;
    int v[8]; int tsum = 0;
#pragma unroll
    for (int j = 0; j < 8; ++j) { v[j] = (base + j < n) ? deg[base + j] : 0; tsum += v[j]; }
    int incl = tsum;
    lds[tid] = incl; __syncthreads();
    for (int off = 1; off < 256; off <<= 1) {
        const int add = (tid >= off) ? lds[tid - off] : 0;
        __syncthreads();
        incl += add; lds[tid] = incl; __syncthreads();
    }
    if (tid == 255) bsum[blockIdx.x] = incl;
    int run = incl - tsum;
#pragma unroll
    for (int j = 0; j < 8; ++j) { if (base + j < n) rowptr[base + j] = run; run += v[j]; }
}

__global__ void __launch_bounds__(256) scan2_kernel(int* __restrict__ bsum, int nb)
{
    __shared__ int lds[256];
    __shared__ int carry_s;
    const int tid = threadIdx.x;
    if (tid == 0) carry_s = 0;
    __syncthreads();
    for (int base = 0; base < nb; base += 256) {
        const int v = (base + tid < nb) ? bsum[base + tid] : 0;
        int incl = v;
        lds[tid] = incl; __syncthreads();
        for (int off = 1; off < 256; off <<= 1) {
            const int add = (tid >= off) ? lds[tid - off] : 0;
            __syncthreads();
            incl += add; lds[tid] = incl; __syncthreads();
        }
        const int total = lds[255];
        const int carry = carry_s;
        if (base + tid < nb) bsum[base + tid] = incl - v + carry;
        __syncthreads();
        if (tid == 0) carry_s = carry + total;
        __syncthreads();
    }
}

__global__ void __launch_bounds__(256) fixup_kernel(int* __restrict__ rowptr,
                                                    const int* __restrict__ bsum, int n,
                                                    int Etot, int* __restrict__ cursor)
{
    int i = blockIdx.x * 256 + threadIdx.x;
    const int stride = gridDim.x * 256;
    if (i == 0) rowptr[n] = Etot;
    for (; i < n; i += stride) {
        const int r = rowptr[i] + bsum[i >> 11];
        rowptr[i] = r; cursor[i] = r;
    }
}

// XCD-sharded placement; nontemporal edge reads keep the streaming re-read from
// evicting the shard's dirty cursor/csr lines out of L2.
__global__ void __launch_bounds__(256) place_kernel(EdgeArgs ea, int Etot, int Nbins,
                                                    int* __restrict__ cursor,
                                                    int* __restrict__ csr)
{
    const int shard = blockIdx.x & 7;
    const int lo = (int)(((long long)shard * Nbins) >> 3);
    const int hi = (int)(((long long)(shard + 1) * Nbins) >> 3);
    int g = (blockIdx.x >> 3) * 256 + threadIdx.x;
    const int stride = (gridDim.x >> 3) * 256;
    for (; g < Etot; g += stride) {
        int t = 0;
        while (g >= ea.ebase[t + 1]) ++t;
        const int e = g - ea.ebase[t];
        const int dst = __builtin_nontemporal_load(&ea.ei[t][ea.E[t] + e]);
        const int gb = ea.binbase[t] + dst;
        if (gb >= lo && gb < hi) {
            const int src = __builtin_nontemporal_load(&ea.ei[t][e]);
            const int pos = atomicAdd(&cursor[gb], 1);
            csr[pos] = src;
        }
    }
}

// ---------------------------------------------------------------- gather64
// wave per dst row (high-degree rows, dst=global): pairwise loads, 8 in flight/wave.
__global__ void __launch_bounds__(256) gather64(const __bf16* __restrict__ x,
                                                const int* __restrict__ rowptr,
                                                const int* __restrict__ csr,
                                                __bf16* __restrict__ agg, int N)
{
    const int lane = threadIdx.x & 63;
    const int l16 = lane & 15, grp = lane >> 4;
    int wv = (blockIdx.x * 256 + threadIdx.x) >> 6;
    const int nwv = (gridDim.x * 256) >> 6;
    for (int row = wv; row < N; row += nwv) {
        const int p0 = rowptr[row], p1 = rowptr[row + 1];
        float acc[8] = {0.f, 0.f, 0.f, 0.f, 0.f, 0.f, 0.f, 0.f};
        int p = p0 + grp * 2;
        for (; p + 2 <= p1; p += 8) {
            const int s0 = csr[p], s1 = csr[p + 1];
            const bf16x8 v0 = *reinterpret_cast<const bf16x8*>(x + (size_t)s0 * 128 + l16 * 8);
            const bf16x8 v1 = *reinterpret_cast<const bf16x8*>(x + (size_t)s1 * 128 + l16 * 8);
#pragma unroll
            for (int j = 0; j < 8; ++j) acc[j] += (float)v0[j] + (float)v1[j];
        }
        if (p < p1) {
            const int s0 = csr[p];
            const bf16x8 v0 = *reinterpret_cast<const bf16x8*>(x + (size_t)s0 * 128 + l16 * 8);
#pragma unroll
            for (int j = 0; j < 8; ++j) acc[j] += (float)v0[j];
        }
#pragma unroll
        for (int j = 0; j < 8; ++j) {
            acc[j] += __shfl_xor(acc[j], 16);
            acc[j] += __shfl_xor(acc[j], 32);
        }
        if (grp == 0) {
            bf16x8 o;
#pragma unroll
            for (int j = 0; j < 8; ++j) o[j] = (__bf16)acc[j];
            *reinterpret_cast<bf16x8*>(agg + (size_t)row * 128 + l16 * 8) = o;
        }
    }
}

// ---------------------------------------------------------------- batched fused gather+GEMM+stats
// R12 structure (dim3(gb,3) grid, 8-lane gather groups, 32 chains/block,
// 4 rows/chain, (256,3), plain hout stores). Single delta vs R12: the gather
// is a 2-DEEP ROW PIPELINE — while row r accumulates, row r+1's csr pair and
// first-2-edge row-data loads are already in flight (covers E[min(deg,2)]~1.7
// of mean-2 edges; deg>2 tail stays serial). Serial chain ~8 -> ~4-5 memory
// epochs per group. All state statically indexed, c/d double-buffer = 32 VGPR
// -> no spill (R10/R13 lesson).
__global__ void __launch_bounds__(256, 3) fgemm_group(ConvGroup cg)
{
    __shared__ __bf16 atile[128 * 128];   // 32 KB
    __shared__ float lsum[128];
    __shared__ float lsq[128];
    const int cj   = blockIdx.y;
    const int M    = cg.M;
    const int tid  = threadIdx.x;
    const int lane = tid & 63;
    const int wv   = tid >> 6;
    if (tid < 128) { lsum[tid] = 0.f; lsq[tid] = 0.f; }

    const int r0 = blockIdx.x * 128;
    const int lrow  = lane & 15;
    const int klane = (lane >> 4) * 8;

    int  car[2]; bool val[2];
#pragma unroll
    for (int rf = 0; rf < 2; ++rf) {
        const int ar = r0 + wv * 32 + rf * 16 + lrow;
        val[rf] = ar < M;
        car[rf] = val[rf] ? ar : (M - 1);
    }
    bf16x8 z8;
#pragma unroll
    for (int j = 0; j < 8; ++j) z8[j] = (__bf16)0.f;

    // early xdst fragment loads (k=128..255 half of A) — overlap with gather
    bf16x8 xd[2][4];
#pragma unroll
    for (int rf = 0; rf < 2; ++rf)
#pragma unroll
        for (int kk = 0; kk < 4; ++kk) {
            const bf16x8 av = *reinterpret_cast<const bf16x8*>(
                cg.xdst + (size_t)car[rf] * 128 + kk * 32 + klane);
            xd[rf][kk] = val[rf] ? av : z8;
        }

    const bool fused = cg.fused[cj] != 0;
    if (fused) {
        const int* __restrict__ rp  = cg.rowptr[cj];
        const int* __restrict__ csr = cg.csr;
        const __bf16* __restrict__ xsrc = cg.xsrc[cj];
        const int grp = tid >> 3, l8 = tid & 7;   // 32 groups of 8 lanes
        int pr[5];
#pragma unroll
        for (int rr = 0; rr < 5; ++rr) {
            int rw = r0 + grp * 4 + rr;
            pr[rr] = rp[rw > M ? M : rw];   // rows >= M collapse to empty ranges
        }
        // pipeline prologue: row 0's csr pair + first-2-edge data
        bf16x8 c0, c1, c2, c3;
        {
            const int q0 = pr[0], q1 = pr[1];
            const int s0 = (q0 < q1) ? csr[q0] : 0;
            const int s1 = (q0 + 1 < q1) ? csr[q0 + 1] : s0;
            const __bf16* a = xsrc + (size_t)s0 * 128 + l8 * 16;
            const __bf16* b = xsrc + (size_t)s1 * 128 + l8 * 16;
            c0 = *reinterpret_cast<const bf16x8*>(a);
            c1 = *reinterpret_cast<const bf16x8*>(a + 8);
            c2 = *reinterpret_cast<const bf16x8*>(b);
            c3 = *reinterpret_cast<const bf16x8*>(b + 8);
        }
#pragma unroll
        for (int rr = 0; rr < 4; ++rr) {
            // issue next row's csr + data loads FIRST (hide under current acc)
            bf16x8 d0 = z8, d1 = z8, d2 = z8, d3 = z8;
            if (rr < 3) {
                const int q0 = pr[rr + 1], q1 = pr[rr + 2];
                const int s0 = (q0 < q1) ? csr[q0] : 0;
                const int s1 = (q0 + 1 < q1) ? csr[q0 + 1] : s0;
                const __bf16* a = xsrc + (size_t)s0 * 128 + l8 * 16;
                const __bf16* b = xsrc + (size_t)s1 * 128 + l8 * 16;
                d0 = *reinterpret_cast<const bf16x8*>(a);
                d1 = *reinterpret_cast<const bf16x8*>(a + 8);
                d2 = *reinterpret_cast<const bf16x8*>(b);
                d3 = *reinterpret_cast<const bf16x8*>(b + 8);
            }
            const int lr = grp * 4 + rr;
            const int p0 = pr[rr], p1 = pr[rr + 1];
            const int deg = p1 - p0;
            float acc[16];
#pragma unroll
            for (int j = 0; j < 16; ++j) acc[j] = 0.f;
            if (deg > 0) {
#pragma unroll
                for (int j = 0; j < 8; ++j) {
                    acc[j]     += (float)c0[j];
                    acc[8 + j] += (float)c1[j];
                }
            }
            if (deg > 1) {
#pragma unroll
                for (int j = 0; j < 8; ++j) {
                    acc[j]     += (float)c2[j];
                    acc[8 + j] += (float)c3[j];
                }
            }
            for (int p = p0 + 2; p < p1; p += 2) {   // rare tail (deg>2), pairwise
                const int s0 = csr[p];
                const int s1 = (p + 1 < p1) ? csr[p + 1] : s0;
                const float m1 = (p + 1 < p1) ? 1.f : 0.f;
                const __bf16* a = xsrc + (size_t)s0 * 128 + l8 * 16;
                const __bf16* b = xsrc + (size_t)s1 * 128 + l8 * 16;
                const bf16x8 t0 = *reinterpret_cast<const bf16x8*>(a);
                const bf16x8 t1 = *reinterpret_cast<const bf16x8*>(a + 8);
                const bf16x8 t2 = *reinterpret_cast<const bf16x8*>(b);
                const bf16x8 t3 = *reinterpret_cast<const bf16x8*>(b + 8);
#pragma unroll
                for (int j = 0; j < 8; ++j) {
                    acc[j]     += (float)t0[j] + m1 * (float)t2[j];
                    acc[8 + j] += (float)t1[j] + m1 * (float)t3[j];
                }
            }
            bf16x8 o0, o1;
#pragma unroll
            for (int j = 0; j < 8; ++j) { o0[j] = (__bf16)acc[j]; o1[j] = (__bf16)acc[8 + j]; }
            // swizzle at 16B-chunk granularity: chunk cb -> cb ^ (lr&7)
            char* base = (char*)atile + lr * 256;
            *reinterpret_cast<bf16x8*>(base + (((l8 * 2    ) << 4) ^ ((lr & 7) << 4))) = o0;
            *reinterpret_cast<bf16x8*>(base + (((l8 * 2 + 1) << 4) ^ ((lr & 7) << 4))) = o1;
            // rotate pipeline
            c0 = d0; c1 = d1; c2 = d2; c3 = d3;
        }
    }
    __syncthreads();

    f32x4 acc[2][8];
#pragma unroll
    for (int rf = 0; rf < 2; ++rf)
#pragma unroll
        for (int cf = 0; cf < 8; ++cf) {
            f32x4 z; z[0] = 0.f; z[1] = 0.f; z[2] = 0.f; z[3] = 0.f;
            acc[rf][cf] = z;
        }

    const __bf16* __restrict__ aggp = cg.agg[cj];
    const __bf16* __restrict__ Wp   = cg.Wp[cj];
#pragma unroll
    for (int ks = 0; ks < 8; ++ks) {
        const int koff = (ks & 3) * 32 + klane;
        bf16x8 a[2];
#pragma unroll
        for (int rf = 0; rf < 2; ++rf) {
            if (ks < 4) {
                if (fused) {
                    const int lr = wv * 32 + rf * 16 + lrow;
                    const char* sp = (const char*)atile + lr * 256
                                   + ((koff * 2) ^ ((lr & 7) << 4));
                    a[rf] = *reinterpret_cast<const bf16x8*>(sp);
                } else {
                    const bf16x8 av = *reinterpret_cast<const bf16x8*>(
                        aggp + (size_t)car[rf] * 128 + koff);
                    a[rf] = val[rf] ? av : z8;
                }
            } else {
                a[rf] = xd[rf][ks - 4];
            }
        }
        const bf16x8* wp8 = reinterpret_cast<const bf16x8*>(Wp) + (size_t)ks * 8 * 64 + lane;
        bf16x8 b[8];
#pragma unroll
        for (int cf = 0; cf < 8; ++cf) b[cf] = wp8[(size_t)cf * 64];
#pragma unroll
        for (int rf = 0; rf < 2; ++rf)
#pragma unroll
            for (int cf = 0; cf < 8; ++cf)
                acc[rf][cf] = __builtin_amdgcn_mfma_f32_16x16x32_bf16(a[rf], b[cf], acc[rf][cf], 0, 0, 0);
    }

    const float* __restrict__ bias = cg.bias[cj];
    __bf16* __restrict__ hout = cg.hout[cj];
    float bc[8];
#pragma unroll
    for (int cf = 0; cf < 8; ++cf) bc[cf] = bias[cf * 16 + lrow];

    const int rb = (lane >> 4) * 4;
#pragma unroll
    for (int cf = 0; cf < 8; ++cf) {
        float s = 0.f, q = 0.f;
#pragma unroll
        for (int rf = 0; rf < 2; ++rf) {
#pragma unroll
            for (int rr = 0; rr < 4; ++rr) {
                const int grow = r0 + wv * 32 + rf * 16 + rb + rr;
                if (grow < M) {
                    const float hv = acc[rf][cf][rr] + bc[cf];
                    hout[(size_t)grow * 128 + cf * 16 + lrow] = (__bf16)hv;
                    s += hv; q += hv * hv;
                }
            }
        }
        s += __shfl_xor(s, 16); s += __shfl_xor(s, 32);
        q += __shfl_xor(q, 16); q += __shfl_xor(q, 32);
        if (lane < 16) {
            atomicAdd(&lsum[cf * 16 + lane], s);
            atomicAdd(&lsq [cf * 16 + lane], q);
        }
    }
    __syncthreads();
    float* __restrict__ st = cg.stats[cj];
    if (tid < 128) {
        atomicAdd(&st[tid],       lsum[tid]);
        atomicAdd(&st[128 + tid], lsq[tid]);
    }
}

// ---------------------------------------------------------------- batched normalize + sum 3 convs
// out = base + sum_j gamma_j*(h_j-mu_j)*rsqrt(var_j+eps)+beta_j ; base = 0 (L0/bf16) or resid (L1/f32)
template<bool F32OUT>
__global__ void __launch_bounds__(256) norm_group(NormGroup ng)
{
    __shared__ float ssc[3][128], ssh[3][128];
    const int tid = threadIdx.x;
    if (tid < 128) {
#pragma unroll
        for (int j = 0; j < 3; ++j) {
            const float mu   = ng.stats[j][tid] * ng.invM;
            const float var  = ng.stats[j][128 + tid] * ng.invM - mu * mu;
            const float scal = ng.gamma[j][tid] * rsqrtf(var + 1e-5f);
            ssc[j][tid] = scal;
            ssh[j][tid] = ng.beta[j][tid] - mu * scal;
        }
    }
    __syncthreads();

    const int t0   = blockIdx.x * 256 + tid;
    const int nthr = gridDim.x * 256;
    const int c0   = (t0 & 15) * 8;
    float sc[3][8], sh[3][8];
#pragma unroll
    for (int j = 0; j < 3; ++j)
#pragma unroll
        for (int k = 0; k < 8; ++k) { sc[j][k] = ssc[j][c0 + k]; sh[j][k] = ssh[j][c0 + k]; }

    const int nch = ng.M * 16;
    for (int ch = t0; ch < nch; ch += nthr) {
        float f[8] = {0.f, 0.f, 0.f, 0.f, 0.f, 0.f, 0.f, 0.f};
#pragma unroll
        for (int j = 0; j < 3; ++j) {
            const bf16x8 hv = *reinterpret_cast<const bf16x8*>(ng.h[j] + (size_t)ch * 8);
#pragma unroll
            for (int k = 0; k < 8; ++k) f[k] += (float)hv[k] * sc[j][k] + sh[j][k];
        }
        if constexpr (F32OUT) {
            const float* rp = ng.resid + (size_t)ch * 8;
            const float4 r0 = *reinterpret_cast<const float4*>(rp);
            const float4 r1 = *reinterpret_cast<const float4*>(rp + 4);
            float* op = (float*)ng.out + (size_t)ch * 8;
            float4 o0, o1;
            o0.x = r0.x + f[0]; o0.y = r0.y + f[1]; o0.z = r0.z + f[2]; o0.w = r0.w + f[3];
            o1.x = r1.x + f[4]; o1.y = r1.y + f[5]; o1.z = r1.z + f[6]; o1.w = r1.w + f[7];
            *reinterpret_cast<float4*>(op)     = o0;
            *reinterpret_cast<float4*>(op + 4) = o1;
        } else {
            bf16x8 ov;
#pragma unroll
            for (int k = 0; k < 8; ++k) ov[k] = (__bf16)f[k];
            *reinterpret_cast<bf16x8*>((__bf16*)ng.out + (size_t)ch * 8) = ov;
        }
    }
}

// ---------------------------------------------------------------- launch
extern "C" void kernel_launch(void* const* d_in, const int* in_sizes, int n_in,
                              void* d_out, int out_size, void* d_ws, size_t ws_size,
                              hipStream_t stream)
{
    const float* xin[3] = {(const float*)d_in[0], (const float*)d_in[1], (const float*)d_in[2]};
    const int N[3] = {in_sizes[0] / 128, in_sizes[1] / 128, in_sizes[2] / 128};
    const float* Wrel  = (const float*)d_in[12];
    const float* brel  = (const float*)d_in[13];
    const float* Wroot = (const float*)d_in[14];
    const float* gamma = (const float*)d_in[15];
    const float* beta  = (const float*)d_in[16];

    // ETS order: a2b b2a a2g g2a b2g g2b a2a b2b g2g  (atom=0,bond=1,global=2)
    const int cs[9] = {0, 1, 0, 2, 1, 2, 0, 1, 2};
    const int cd[9] = {1, 0, 2, 0, 2, 1, 0, 1, 2};
    // dst-groups: convs (ETS idx) per dst type
    const int gconv[3][3] = {{1, 3, 6},   // dst=atom : b2a, g2a, a2a
                             {0, 5, 7},   // dst=bond : a2b, g2b, b2b
                             {2, 4, 8}};  // dst=global: a2g, b2g, g2g

    const size_t nA = (size_t)N[0] * 128, nB = (size_t)N[1] * 128, nG = (size_t)N[2] * 128;
    const size_t off[3] = {0, nA, nA + nB};
    const size_t xtot = nA + nB + nG;
    size_t maxN = (size_t)N[0];
    if ((size_t)N[1] > maxN) maxN = N[1];
    if ((size_t)N[2] > maxN) maxN = N[2];

    // edge/bin geometry
    EdgeArgs ea;
    int Etot = 0, Nbins = 0;
    ea.ebase[0] = 0;
    for (int t = 0; t < 9; ++t) {
        ea.ei[t] = (const int*)d_in[3 + t];
        ea.E[t]  = in_sizes[3 + t] / 2;
        ea.ebase[t + 1] = ea.ebase[t] + ea.E[t];
        ea.binbase[t] = Nbins;
        Nbins += N[cd[t]];
    }
    Etot = ea.ebase[9];
    const int nb1 = (Nbins + SCHUNK - 1) / SCHUNK;

    // ws layout (~410 MB)
    auto al = [](size_t x) { return (x + 15) & ~(size_t)15; };
    char* w = (char*)d_ws;
    __bf16* x0b   = (__bf16*)w;  w += al(xtot * 2);
    __bf16* x1    = (__bf16*)w;  w += al(xtot * 2);
    __bf16* aggb  = (__bf16*)w;  w += al(2 * maxN * 128 * 2);
    __bf16* hbuf  = (__bf16*)w;  w += al(3 * maxN * 128 * 2);
    float*  stats = (float*)w;   w += al(18 * 256 * 4);
    __bf16* Wp    = (__bf16*)w;  w += al((size_t)18 * 32768 * 2);
    int*    deg   = (int*)w;     w += al((size_t)Nbins * 4);
    int*    rowptr= (int*)w;     w += al(((size_t)Nbins + 1) * 4);
    int*    cursor= (int*)w;     w += al((size_t)Nbins * 4);
    int*    csr   = (int*)w;     w += al((size_t)Etot * 4);
    int*    bsum  = (int*)w;     w += al((size_t)nb1 * 4);
    (void)ws_size; (void)n_in; (void)out_size;

    pack_w<<<288, 256, 0, stream>>>(Wrel, Wroot, Wp);
    for (int k = 0; k < 3; ++k) {
        const int n8 = (int)(((k == 0 ? nA : k == 1 ? nB : nG)) / 8);
        int cb = (n8 + 255) / 256; if (cb > 2048) cb = 2048;
        cvt_kernel<<<cb, 256, 0, stream>>>(xin[k], x0b + off[k], n8);
    }
    hipMemsetAsync(deg, 0, (size_t)Nbins * 4, stream);
    hipMemsetAsync(stats, 0, 18 * 256 * 4, stream);

    int eb = (Etot + 255) / 256; if (eb > 2048) eb = 2048;
    hist_kernel<<<eb, 256, 0, stream>>>(ea, Etot, deg);
    scan1_kernel<<<nb1, 256, 0, stream>>>(deg, Nbins, rowptr, bsum);
    scan2_kernel<<<1, 256, 0, stream>>>(bsum, nb1);
    int fb = (Nbins + 255) / 256; if (fb > 2048) fb = 2048;
    fixup_kernel<<<fb, 256, 0, stream>>>(rowptr, bsum, Nbins, Etot, cursor);
    place_kernel<<<2048, 256, 0, stream>>>(ea, Etot, Nbins, cursor, csr);

    float* dout = (float*)d_out;

    for (int L = 0; L < 2; ++L) {
        const __bf16* xb = (L == 0) ? x0b : x1;

        // pre-gather high-degree (deg>=8) convs: a2g (ets 2), b2g (ets 4)
        {
            const int Ng = N[2];
            int gb2 = (Ng * 64 + 255) / 256; if (gb2 > 2048) gb2 = 2048; if (gb2 < 1) gb2 = 1;
            gather64<<<gb2, 256, 0, stream>>>(xb + off[0], rowptr + ea.binbase[2], csr,
                                              aggb, Ng);
            gather64<<<gb2, 256, 0, stream>>>(xb + off[1], rowptr + ea.binbase[4], csr,
                                              aggb + maxN * 128, Ng);
        }

        for (int g = 0; g < 3; ++g) {
            const int d  = g;           // dst type == group index
            const int Nd = N[d];
            ConvGroup cg;
            NormGroup ng;
            cg.xdst = xb + off[d];
            cg.csr  = csr;
            cg.M    = Nd;
            for (int j = 0; j < 3; ++j) {
                const int et = gconv[g][j];
                const int li = L * 9 + et;
                cg.rowptr[j] = rowptr + ea.binbase[et];
                cg.xsrc[j]   = xb + off[cs[et]];
                cg.Wp[j]     = Wp + (size_t)li * 32768;
                cg.bias[j]   = brel + li * 128;
                cg.stats[j]  = stats + li * 256;
                cg.hout[j]   = hbuf + (size_t)j * maxN * 128;
                const bool hi = (et == 2) || (et == 4);
                cg.fused[j]  = hi ? 0 : 1;
                cg.agg[j]    = (et == 2) ? aggb : (et == 4 ? aggb + maxN * 128 : (const __bf16*)nullptr);
                ng.h[j]      = cg.hout[j];
                ng.stats[j]  = cg.stats[j];
                ng.gamma[j]  = gamma + li * 128;
                ng.beta[j]   = beta + li * 128;
            }
            const int gb = (Nd + 127) / 128;
            fgemm_group<<<dim3(gb, 3), 256, 0, stream>>>(cg);

            ng.invM = 1.0f / (float)Nd;
            ng.M    = Nd;
            const long long nch = (long long)Nd * 16;
            int nb = (int)((nch + 255) / 256); if (nb > 2048) nb = 2048;
            if (L == 0) {
                ng.resid = nullptr;
                ng.out   = (void*)(x1 + off[d]);
                norm_group<false><<<nb, 256, 0, stream>>>(ng);
            } else {
                ng.resid = xin[d];
                ng.out   = (void*)(dout + off[d]);
                norm_group<true><<<nb, 256, 0, stream>>>(ng);
            }
        }
    }
}

// Round 17
// 1395.533 us; speedup vs baseline: 1.3857x; 1.0118x over previous
//
#include <hip/hip_runtime.h>
#include <hip/hip_bf16.h>

typedef __bf16 bf16x8 __attribute__((ext_vector_type(8)));
typedef float  f32x4  __attribute__((ext_vector_type(4)));

#define SCHUNK 2048  // elements per scan1 block (256 thr * 8)

struct EdgeArgs {
    const int* ei[9];
    int E[9];
    int ebase[10];   // prefix over edges
    int binbase[9];  // prefix over dst bins
};

struct ConvGroup {          // 3 convs sharing the same dst type
    const int* rowptr[3];
    const __bf16* xsrc[3];
    const __bf16* agg[3];   // pre-gathered A (unfused convs)
    const __bf16* Wp[3];
    const float* bias[3];
    float* stats[3];
    __bf16* hout[3];
    const __bf16* xdst;
    const int* csr;
    int fused[3];
    int M;
};

struct NormGroup {
    const __bf16* h[3];
    const float* stats[3];
    const float* gamma[3];
    const float* beta[3];
    const float* resid;     // f32 base (L1) or null
    void* out;
    float invM;
    int M;
};

// ---------------------------------------------------------------- pack W
// Layout: [li=L*9+i][ks(8)][cf(8)][lane(64)][j(8)]  (bf16)
// k = ks*32 + (lane>>4)*8 + j ; col = cf*16 + (lane&15)
__global__ void __launch_bounds__(256) pack_w(const float* __restrict__ Wrel,
                                              const float* __restrict__ Wroot,
                                              __bf16* __restrict__ Wp)
{
    const int idx = blockIdx.x * 256 + threadIdx.x;
    if (idx >= 2 * 9 * 8 * 8 * 64) return;
    const int lane = idx & 63;
    int t = idx >> 6;
    const int cf = t & 7; t >>= 3;
    const int ks = t & 7; t >>= 3;
    const int li = t;  // 0..17
    const int col = cf * 16 + (lane & 15);
    const int kb  = ks * 32 + (lane >> 4) * 8;
    bf16x8 o;
#pragma unroll
    for (int j = 0; j < 8; ++j) {
        const int k = kb + j;
        const float v = (k < 128)
            ? Wrel [((size_t)li * 128 + k)        * 128 + col]
            : Wroot[((size_t)li * 128 + (k - 128)) * 128 + col];
        o[j] = (__bf16)v;
    }
    *reinterpret_cast<bf16x8*>(Wp + (size_t)idx * 8) = o;
}

// ---------------------------------------------------------------- f32 -> bf16 convert
__global__ void __launch_bounds__(256) cvt_kernel(const float* __restrict__ in,
                                                  __bf16* __restrict__ out, int n8)
{
    int i = blockIdx.x * 256 + threadIdx.x;
    const int stride = gridDim.x * 256;
    for (; i < n8; i += stride) {
        const float4 f0 = *reinterpret_cast<const float4*>(in + (size_t)i * 8);
        const float4 f1 = *reinterpret_cast<const float4*>(in + (size_t)i * 8 + 4);
        bf16x8 o;
        o[0] = (__bf16)f0.x; o[1] = (__bf16)f0.y; o[2] = (__bf16)f0.z; o[3] = (__bf16)f0.w;
        o[4] = (__bf16)f1.x; o[5] = (__bf16)f1.y; o[6] = (__bf16)f1.z; o[7] = (__bf16)f1.w;
        *reinterpret_cast<bf16x8*>(out + (size_t)i * 8) = o;
    }
}

// ---------------------------------------------------------------- CSR build
__global__ void __launch_bounds__(256) hist_kernel(EdgeArgs ea, int Etot,
                                                   int* __restrict__ deg)
{
    int g = blockIdx.x * 256 + threadIdx.x;
    const int stride = gridDim.x * 256;
    for (; g < Etot; g += stride) {
        int t = 0;
        while (g >= ea.ebase[t + 1]) ++t;
        const int e = g - ea.ebase[t];
        const int dst = __builtin_nontemporal_load(&ea.ei[t][ea.E[t] + e]);
        atomicAdd(&deg[ea.binbase[t] + dst], 1);
    }
}

__global__ void __launch_bounds__(256) scan1_kernel(const int* __restrict__ deg, int n,
                                                    int* __restrict__ rowptr,
                                                    int* __restrict__ bsum)
{
    __shared__ int lds[256];
    const int tid = threadIdx.x;
    const int base = blockIdx.x * SCHUNK + tid * 8;
    int v[8]; int tsum = 0;
#pragma unroll
    for (int j = 0; j < 8; ++j) { v[j] = (base + j < n) ? deg[base + j] : 0; tsum += v[j]; }
    int incl = tsum;
    lds[tid] = incl; __syncthreads();
    for (int off = 1; off < 256; off <<= 1) {
        const int add = (tid >= off) ? lds[tid - off] : 0;
        __syncthreads();
        incl += add; lds[tid] = incl; __syncthreads();
    }
    if (tid == 255) bsum[blockIdx.x] = incl;
    int run = incl - tsum;
#pragma unroll
    for (int j = 0; j < 8; ++j) { if (base + j < n) rowptr[base + j] = run; run += v[j]; }
}

__global__ void __launch_bounds__(256) scan2_kernel(int* __restrict__ bsum, int nb)
{
    __shared__ int lds[256];
    __shared__ int carry_s;
    const int tid = threadIdx.x;
    if (tid == 0) carry_s = 0;
    __syncthreads();
    for (int base = 0; base < nb; base += 256) {
        const int v = (base + tid < nb) ? bsum[base + tid] : 0;
        int incl = v;
        lds[tid] = incl; __syncthreads();
        for (int off = 1; off < 256; off <<= 1) {
            const int add = (tid >= off) ? lds[tid - off] : 0;
            __syncthreads();
            incl += add; lds[tid] = incl; __syncthreads();
        }
        const int total = lds[255];
        const int carry = carry_s;
        if (base + tid < nb) bsum[base + tid] = incl - v + carry;
        __syncthreads();
        if (tid == 0) carry_s = carry + total;
        __syncthreads();
    }
}

__global__ void __launch_bounds__(256) fixup_kernel(int* __restrict__ rowptr,
                                                    const int* __restrict__ bsum, int n,
                                                    int Etot, int* __restrict__ cursor)
{
    int i = blockIdx.x * 256 + threadIdx.x;
    const int stride = gridDim.x * 256;
    if (i == 0) rowptr[n] = Etot;
    for (; i < n; i += stride) {
        const int r = rowptr[i] + bsum[i >> 11];
        rowptr[i] = r; cursor[i] = r;
    }
}

// XCD-sharded placement; nontemporal edge reads keep the streaming re-read from
// evicting the shard's dirty cursor/csr lines out of L2.
__global__ void __launch_bounds__(256) place_kernel(EdgeArgs ea, int Etot, int Nbins,
                                                    int* __restrict__ cursor,
                                                    int* __restrict__ csr)
{
    const int shard = blockIdx.x & 7;
    const int lo = (int)(((long long)shard * Nbins) >> 3);
    const int hi = (int)(((long long)(shard + 1) * Nbins) >> 3);
    int g = (blockIdx.x >> 3) * 256 + threadIdx.x;
    const int stride = (gridDim.x >> 3) * 256;
    for (; g < Etot; g += stride) {
        int t = 0;
        while (g >= ea.ebase[t + 1]) ++t;
        const int e = g - ea.ebase[t];
        const int dst = __builtin_nontemporal_load(&ea.ei[t][ea.E[t] + e]);
        const int gb = ea.binbase[t] + dst;
        if (gb >= lo && gb < hi) {
            const int src = __builtin_nontemporal_load(&ea.ei[t][e]);
            const int pos = atomicAdd(&cursor[gb], 1);
            csr[pos] = src;
        }
    }
}

// ---------------------------------------------------------------- gather64
// wave per dst row (high-degree rows, dst=global): pairwise loads, 8 in flight/wave.
__global__ void __launch_bounds__(256) gather64(const __bf16* __restrict__ x,
                                                const int* __restrict__ rowptr,
                                                const int* __restrict__ csr,
                                                __bf16* __restrict__ agg, int N)
{
    const int lane = threadIdx.x & 63;
    const int l16 = lane & 15, grp = lane >> 4;
    int wv = (blockIdx.x * 256 + threadIdx.x) >> 6;
    const int nwv = (gridDim.x * 256) >> 6;
    for (int row = wv; row < N; row += nwv) {
        const int p0 = rowptr[row], p1 = rowptr[row + 1];
        float acc[8] = {0.f, 0.f, 0.f, 0.f, 0.f, 0.f, 0.f, 0.f};
        int p = p0 + grp * 2;
        for (; p + 2 <= p1; p += 8) {
            const int s0 = csr[p], s1 = csr[p + 1];
            const bf16x8 v0 = *reinterpret_cast<const bf16x8*>(x + (size_t)s0 * 128 + l16 * 8);
            const bf16x8 v1 = *reinterpret_cast<const bf16x8*>(x + (size_t)s1 * 128 + l16 * 8);
#pragma unroll
            for (int j = 0; j < 8; ++j) acc[j] += (float)v0[j] + (float)v1[j];
        }
        if (p < p1) {
            const int s0 = csr[p];
            const bf16x8 v0 = *reinterpret_cast<const bf16x8*>(x + (size_t)s0 * 128 + l16 * 8);
#pragma unroll
            for (int j = 0; j < 8; ++j) acc[j] += (float)v0[j];
        }
#pragma unroll
        for (int j = 0; j < 8; ++j) {
            acc[j] += __shfl_xor(acc[j], 16);
            acc[j] += __shfl_xor(acc[j], 32);
        }
        if (grp == 0) {
            bf16x8 o;
#pragma unroll
            for (int j = 0; j < 8; ++j) o[j] = (__bf16)acc[j];
            *reinterpret_cast<bf16x8*>(agg + (size_t)row * 128 + l16 * 8) = o;
        }
    }
}

// ---------------------------------------------------------------- batched fused gather+GEMM+stats
// R16 structure (dim3(gb,3), 8-lane gather groups, 32 chains/block, 4 rows/chain,
// (256,3)). Delta vs R16: FULLY FLATTENED gather prefetch — all 8 csr-index
// loads (2/row x 4 rows) issue in one parallel epoch, then all 16 row-data
// loads in a second epoch, then row-by-row accumulate (deg>2 tails serial).
// Common-case chain: 2 memory epochs vs R16's ~4. Register budget: 16 bf16x8
// data (64) + 8 idx + acc 16 + xd 32 + addr ~20 = ~140 < the 170 ceiling that
// (256,3) allows (R10's spill was the (256,4)=128 cap, not prefetch per se).
// All arrays fully unrolled/statically indexed.
__global__ void __launch_bounds__(256, 3) fgemm_group(ConvGroup cg)
{
    __shared__ __bf16 atile[128 * 128];   // 32 KB
    __shared__ float lsum[128];
    __shared__ float lsq[128];
    const int cj   = blockIdx.y;
    const int M    = cg.M;
    const int tid  = threadIdx.x;
    const int lane = tid & 63;
    const int wv   = tid >> 6;
    if (tid < 128) { lsum[tid] = 0.f; lsq[tid] = 0.f; }

    const int r0 = blockIdx.x * 128;
    const int lrow  = lane & 15;
    const int klane = (lane >> 4) * 8;

    int  car[2]; bool val[2];
#pragma unroll
    for (int rf = 0; rf < 2; ++rf) {
        const int ar = r0 + wv * 32 + rf * 16 + lrow;
        val[rf] = ar < M;
        car[rf] = val[rf] ? ar : (M - 1);
    }
    bf16x8 z8;
#pragma unroll
    for (int j = 0; j < 8; ++j) z8[j] = (__bf16)0.f;

    // early xdst fragment loads (k=128..255 half of A) — overlap with gather
    bf16x8 xd[2][4];
#pragma unroll
    for (int rf = 0; rf < 2; ++rf)
#pragma unroll
        for (int kk = 0; kk < 4; ++kk) {
            const bf16x8 av = *reinterpret_cast<const bf16x8*>(
                cg.xdst + (size_t)car[rf] * 128 + kk * 32 + klane);
            xd[rf][kk] = val[rf] ? av : z8;
        }

    const bool fused = cg.fused[cj] != 0;
    if (fused) {
        const int* __restrict__ rp  = cg.rowptr[cj];
        const int* __restrict__ csr = cg.csr;
        const __bf16* __restrict__ xsrc = cg.xsrc[cj];
        const int grp = tid >> 3, l8 = tid & 7;   // 32 groups of 8 lanes
        int pr[5];
#pragma unroll
        for (int rr = 0; rr < 5; ++rr) {
            int rw = r0 + grp * 4 + rr;
            pr[rr] = rp[rw > M ? M : rw];   // rows >= M collapse to empty ranges
        }
        // epoch 1: ALL csr-index loads (first 2 edges of each row), parallel
        int sA[4], sB[4];
#pragma unroll
        for (int rr = 0; rr < 4; ++rr) {
            const int p0 = pr[rr], p1 = pr[rr + 1];
            sA[rr] = (p0 < p1) ? csr[p0] : 0;
            sB[rr] = (p0 + 1 < p1) ? csr[p0 + 1] : sA[rr];
        }
        // epoch 2: ALL 16 row-data loads, parallel
        bf16x8 va0[4], va1[4], vb0[4], vb1[4];
#pragma unroll
        for (int rr = 0; rr < 4; ++rr) {
            const __bf16* a = xsrc + (size_t)sA[rr] * 128 + l8 * 16;
            const __bf16* b = xsrc + (size_t)sB[rr] * 128 + l8 * 16;
            va0[rr] = *reinterpret_cast<const bf16x8*>(a);
            va1[rr] = *reinterpret_cast<const bf16x8*>(a + 8);
            vb0[rr] = *reinterpret_cast<const bf16x8*>(b);
            vb1[rr] = *reinterpret_cast<const bf16x8*>(b + 8);
        }
        // epoch 3: accumulate + rare tails (deg>2) + swizzled LDS store
#pragma unroll
        for (int rr = 0; rr < 4; ++rr) {
            const int lr = grp * 4 + rr;
            const int p0 = pr[rr], p1 = pr[rr + 1];
            const int deg = p1 - p0;
            float acc[16];
#pragma unroll
            for (int j = 0; j < 16; ++j) acc[j] = 0.f;
            if (deg > 0) {
#pragma unroll
                for (int j = 0; j < 8; ++j) {
                    acc[j]     += (float)va0[rr][j];
                    acc[8 + j] += (float)va1[rr][j];
                }
            }
            if (deg > 1) {
#pragma unroll
                for (int j = 0; j < 8; ++j) {
                    acc[j]     += (float)vb0[rr][j];
                    acc[8 + j] += (float)vb1[rr][j];
                }
            }
            for (int p = p0 + 2; p < p1; p += 2) {   // tail, pairwise
                const int s0 = csr[p];
                const int s1 = (p + 1 < p1) ? csr[p + 1] : s0;
                const float m1 = (p + 1 < p1) ? 1.f : 0.f;
                const __bf16* a = xsrc + (size_t)s0 * 128 + l8 * 16;
                const __bf16* b = xsrc + (size_t)s1 * 128 + l8 * 16;
                const bf16x8 t0 = *reinterpret_cast<const bf16x8*>(a);
                const bf16x8 t1 = *reinterpret_cast<const bf16x8*>(a + 8);
                const bf16x8 t2 = *reinterpret_cast<const bf16x8*>(b);
                const bf16x8 t3 = *reinterpret_cast<const bf16x8*>(b + 8);
#pragma unroll
                for (int j = 0; j < 8; ++j) {
                    acc[j]     += (float)t0[j] + m1 * (float)t2[j];
                    acc[8 + j] += (float)t1[j] + m1 * (float)t3[j];
                }
            }
            bf16x8 o0, o1;
#pragma unroll
            for (int j = 0; j < 8; ++j) { o0[j] = (__bf16)acc[j]; o1[j] = (__bf16)acc[8 + j]; }
            // swizzle at 16B-chunk granularity: chunk cb -> cb ^ (lr&7)
            char* base = (char*)atile + lr * 256;
            *reinterpret_cast<bf16x8*>(base + (((l8 * 2    ) << 4) ^ ((lr & 7) << 4))) = o0;
            *reinterpret_cast<bf16x8*>(base + (((l8 * 2 + 1) << 4) ^ ((lr & 7) << 4))) = o1;
        }
    }
    __syncthreads();

    f32x4 acc[2][8];
#pragma unroll
    for (int rf = 0; rf < 2; ++rf)
#pragma unroll
        for (int cf = 0; cf < 8; ++cf) {
            f32x4 z; z[0] = 0.f; z[1] = 0.f; z[2] = 0.f; z[3] = 0.f;
            acc[rf][cf] = z;
        }

    const __bf16* __restrict__ aggp = cg.agg[cj];
    const __bf16* __restrict__ Wp   = cg.Wp[cj];
#pragma unroll
    for (int ks = 0; ks < 8; ++ks) {
        const int koff = (ks & 3) * 32 + klane;
        bf16x8 a[2];
#pragma unroll
        for (int rf = 0; rf < 2; ++rf) {
            if (ks < 4) {
                if (fused) {
                    const int lr = wv * 32 + rf * 16 + lrow;
                    const char* sp = (const char*)atile + lr * 256
                                   + ((koff * 2) ^ ((lr & 7) << 4));
                    a[rf] = *reinterpret_cast<const bf16x8*>(sp);
                } else {
                    const bf16x8 av = *reinterpret_cast<const bf16x8*>(
                        aggp + (size_t)car[rf] * 128 + koff);
                    a[rf] = val[rf] ? av : z8;
                }
            } else {
                a[rf] = xd[rf][ks - 4];
            }
        }
        const bf16x8* wp8 = reinterpret_cast<const bf16x8*>(Wp) + (size_t)ks * 8 * 64 + lane;
        bf16x8 b[8];
#pragma unroll
        for (int cf = 0; cf < 8; ++cf) b[cf] = wp8[(size_t)cf * 64];
#pragma unroll
        for (int rf = 0; rf < 2; ++rf)
#pragma unroll
            for (int cf = 0; cf < 8; ++cf)
                acc[rf][cf] = __builtin_amdgcn_mfma_f32_16x16x32_bf16(a[rf], b[cf], acc[rf][cf], 0, 0, 0);
    }

    const float* __restrict__ bias = cg.bias[cj];
    __bf16* __restrict__ hout = cg.hout[cj];
    float bc[8];
#pragma unroll
    for (int cf = 0; cf < 8; ++cf) bc[cf] = bias[cf * 16 + lrow];

    const int rb = (lane >> 4) * 4;
#pragma unroll
    for (int cf = 0; cf < 8; ++cf) {
        float s = 0.f, q = 0.f;
#pragma unroll
        for (int rf = 0; rf < 2; ++rf) {
#pragma unroll
            for (int rr = 0; rr < 4; ++rr) {
                const int grow = r0 + wv * 32 + rf * 16 + rb + rr;
                if (grow < M) {
                    const float hv = acc[rf][cf][rr] + bc[cf];
                    hout[(size_t)grow * 128 + cf * 16 + lrow] = (__bf16)hv;
                    s += hv; q += hv * hv;
                }
            }
        }
        s += __shfl_xor(s, 16); s += __shfl_xor(s, 32);
        q += __shfl_xor(q, 16); q += __shfl_xor(q, 32);
        if (lane < 16) {
            atomicAdd(&lsum[cf * 16 + lane], s);
            atomicAdd(&lsq [cf * 16 + lane], q);
        }
    }
    __syncthreads();
    float* __restrict__ st = cg.stats[cj];
    if (tid < 128) {
        atomicAdd(&st[tid],       lsum[tid]);
        atomicAdd(&st[128 + tid], lsq[tid]);
    }
}

// ---------------------------------------------------------------- batched normalize + sum 3 convs
// out = base + sum_j gamma_j*(h_j-mu_j)*rsqrt(var_j+eps)+beta_j ; base = 0 (L0/bf16) or resid (L1/f32)
template<bool F32OUT>
__global__ void __launch_bounds__(256) norm_group(NormGroup ng)
{
    __shared__ float ssc[3][128], ssh[3][128];
    const int tid = threadIdx.x;
    if (tid < 128) {
#pragma unroll
        for (int j = 0; j < 3; ++j) {
            const float mu   = ng.stats[j][tid] * ng.invM;
            const float var  = ng.stats[j][128 + tid] * ng.invM - mu * mu;
            const float scal = ng.gamma[j][tid] * rsqrtf(var + 1e-5f);
            ssc[j][tid] = scal;
            ssh[j][tid] = ng.beta[j][tid] - mu * scal;
        }
    }
    __syncthreads();

    const int t0   = blockIdx.x * 256 + tid;
    const int nthr = gridDim.x * 256;
    const int c0   = (t0 & 15) * 8;
    float sc[3][8], sh[3][8];
#pragma unroll
    for (int j = 0; j < 3; ++j)
#pragma unroll
        for (int k = 0; k < 8; ++k) { sc[j][k] = ssc[j][c0 + k]; sh[j][k] = ssh[j][c0 + k]; }

    const int nch = ng.M * 16;
    for (int ch = t0; ch < nch; ch += nthr) {
        float f[8] = {0.f, 0.f, 0.f, 0.f, 0.f, 0.f, 0.f, 0.f};
#pragma unroll
        for (int j = 0; j < 3; ++j) {
            const bf16x8 hv = *reinterpret_cast<const bf16x8*>(ng.h[j] + (size_t)ch * 8);
#pragma unroll
            for (int k = 0; k < 8; ++k) f[k] += (float)hv[k] * sc[j][k] + sh[j][k];
        }
        if constexpr (F32OUT) {
            const float* rp = ng.resid + (size_t)ch * 8;
            const float4 r0 = *reinterpret_cast<const float4*>(rp);
            const float4 r1 = *reinterpret_cast<const float4*>(rp + 4);
            float* op = (float*)ng.out + (size_t)ch * 8;
            float4 o0, o1;
            o0.x = r0.x + f[0]; o0.y = r0.y + f[1]; o0.z = r0.z + f[2]; o0.w = r0.w + f[3];
            o1.x = r1.x + f[4]; o1.y = r1.y + f[5]; o1.z = r1.z + f[6]; o1.w = r1.w + f[7];
            *reinterpret_cast<float4*>(op)     = o0;
            *reinterpret_cast<float4*>(op + 4) = o1;
        } else {
            bf16x8 ov;
#pragma unroll
            for (int k = 0; k < 8; ++k) ov[k] = (__bf16)f[k];
            *reinterpret_cast<bf16x8*>((__bf16*)ng.out + (size_t)ch * 8) = ov;
        }
    }
}

// ---------------------------------------------------------------- launch
extern "C" void kernel_launch(void* const* d_in, const int* in_sizes, int n_in,
                              void* d_out, int out_size, void* d_ws, size_t ws_size,
                              hipStream_t stream)
{
    const float* xin[3] = {(const float*)d_in[0], (const float*)d_in[1], (const float*)d_in[2]};
    const int N[3] = {in_sizes[0] / 128, in_sizes[1] / 128, in_sizes[2] / 128};
    const float* Wrel  = (const float*)d_in[12];
    const float* brel  = (const float*)d_in[13];
    const float* Wroot = (const float*)d_in[14];
    const float* gamma = (const float*)d_in[15];
    const float* beta  = (const float*)d_in[16];

    // ETS order: a2b b2a a2g g2a b2g g2b a2a b2b g2g  (atom=0,bond=1,global=2)
    const int cs[9] = {0, 1, 0, 2, 1, 2, 0, 1, 2};
    const int cd[9] = {1, 0, 2, 0, 2, 1, 0, 1, 2};
    // dst-groups: convs (ETS idx) per dst type
    const int gconv[3][3] = {{1, 3, 6},   // dst=atom : b2a, g2a, a2a
                             {0, 5, 7},   // dst=bond : a2b, g2b, b2b
                             {2, 4, 8}};  // dst=global: a2g, b2g, g2g

    const size_t nA = (size_t)N[0] * 128, nB = (size_t)N[1] * 128, nG = (size_t)N[2] * 128;
    const size_t off[3] = {0, nA, nA + nB};
    const size_t xtot = nA + nB + nG;
    size_t maxN = (size_t)N[0];
    if ((size_t)N[1] > maxN) maxN = N[1];
    if ((size_t)N[2] > maxN) maxN = N[2];

    // edge/bin geometry
    EdgeArgs ea;
    int Etot = 0, Nbins = 0;
    ea.ebase[0] = 0;
    for (int t = 0; t < 9; ++t) {
        ea.ei[t] = (const int*)d_in[3 + t];
        ea.E[t]  = in_sizes[3 + t] / 2;
        ea.ebase[t + 1] = ea.ebase[t] + ea.E[t];
        ea.binbase[t] = Nbins;
        Nbins += N[cd[t]];
    }
    Etot = ea.ebase[9];
    const int nb1 = (Nbins + SCHUNK - 1) / SCHUNK;

    // ws layout (~410 MB)
    auto al = [](size_t x) { return (x + 15) & ~(size_t)15; };
    char* w = (char*)d_ws;
    __bf16* x0b   = (__bf16*)w;  w += al(xtot * 2);
    __bf16* x1    = (__bf16*)w;  w += al(xtot * 2);
    __bf16* aggb  = (__bf16*)w;  w += al(2 * maxN * 128 * 2);
    __bf16* hbuf  = (__bf16*)w;  w += al(3 * maxN * 128 * 2);
    float*  stats = (float*)w;   w += al(18 * 256 * 4);
    __bf16* Wp    = (__bf16*)w;  w += al((size_t)18 * 32768 * 2);
    int*    deg   = (int*)w;     w += al((size_t)Nbins * 4);
    int*    rowptr= (int*)w;     w += al(((size_t)Nbins + 1) * 4);
    int*    cursor= (int*)w;     w += al((size_t)Nbins * 4);
    int*    csr   = (int*)w;     w += al((size_t)Etot * 4);
    int*    bsum  = (int*)w;     w += al((size_t)nb1 * 4);
    (void)ws_size; (void)n_in; (void)out_size;

    pack_w<<<288, 256, 0, stream>>>(Wrel, Wroot, Wp);
    for (int k = 0; k < 3; ++k) {
        const int n8 = (int)(((k == 0 ? nA : k == 1 ? nB : nG)) / 8);
        int cb = (n8 + 255) / 256; if (cb > 2048) cb = 2048;
        cvt_kernel<<<cb, 256, 0, stream>>>(xin[k], x0b + off[k], n8);
    }
    hipMemsetAsync(deg, 0, (size_t)Nbins * 4, stream);
    hipMemsetAsync(stats, 0, 18 * 256 * 4, stream);

    int eb = (Etot + 255) / 256; if (eb > 2048) eb = 2048;
    hist_kernel<<<eb, 256, 0, stream>>>(ea, Etot, deg);
    scan1_kernel<<<nb1, 256, 0, stream>>>(deg, Nbins, rowptr, bsum);
    scan2_kernel<<<1, 256, 0, stream>>>(bsum, nb1);
    int fb = (Nbins + 255) / 256; if (fb > 2048) fb = 2048;
    fixup_kernel<<<fb, 256, 0, stream>>>(rowptr, bsum, Nbins, Etot, cursor);
    place_kernel<<<2048, 256, 0, stream>>>(ea, Etot, Nbins, cursor, csr);

    float* dout = (float*)d_out;

    for (int L = 0; L < 2; ++L) {
        const __bf16* xb = (L == 0) ? x0b : x1;

        // pre-gather high-degree (deg>=8) convs: a2g (ets 2), b2g (ets 4)
        {
            const int Ng = N[2];
            int gb2 = (Ng * 64 + 255) / 256; if (gb2 > 2048) gb2 = 2048; if (gb2 < 1) gb2 = 1;
            gather64<<<gb2, 256, 0, stream>>>(xb + off[0], rowptr + ea.binbase[2], csr,
                                              aggb, Ng);
            gather64<<<gb2, 256, 0, stream>>>(xb + off[1], rowptr + ea.binbase[4], csr,
                                              aggb + maxN * 128, Ng);
        }

        for (int g = 0; g < 3; ++g) {
            const int d  = g;           // dst type == group index
            const int Nd = N[d];
            ConvGroup cg;
            NormGroup ng;
            cg.xdst = xb + off[d];
            cg.csr  = csr;
            cg.M    = Nd;
            for (int j = 0; j < 3; ++j) {
                const int et = gconv[g][j];
                const int li = L * 9 + et;
                cg.rowptr[j] = rowptr + ea.binbase[et];
                cg.xsrc[j]   = xb + off[cs[et]];
                cg.Wp[j]     = Wp + (size_t)li * 32768;
                cg.bias[j]   = brel + li * 128;
                cg.stats[j]  = stats + li * 256;
                cg.hout[j]   = hbuf + (size_t)j * maxN * 128;
                const bool hi = (et == 2) || (et == 4);
                cg.fused[j]  = hi ? 0 : 1;
                cg.agg[j]    = (et == 2) ? aggb : (et == 4 ? aggb + maxN * 128 : (const __bf16*)nullptr);
                ng.h[j]      = cg.hout[j];
                ng.stats[j]  = cg.stats[j];
                ng.gamma[j]  = gamma + li * 128;
                ng.beta[j]   = beta + li * 128;
            }
            const int gb = (Nd + 127) / 128;
            fgemm_group<<<dim3(gb, 3), 256, 0, stream>>>(cg);

            ng.invM = 1.0f / (float)Nd;
            ng.M    = Nd;
            const long long nch = (long long)Nd * 16;
            int nb = (int)((nch + 255) / 256); if (nb > 2048) nb = 2048;
            if (L == 0) {
                ng.resid = nullptr;
                ng.out   = (void*)(x1 + off[d]);
                norm_group<false><<<nb, 256, 0, stream>>>(ng);
            } else {
                ng.resid = xin[d];
                ng.out   = (void*)(dout + off[d]);
                norm_group<true><<<nb, 256, 0, stream>>>(ng);
            }
        }
    }
}

// Round 18
// 1327.221 us; speedup vs baseline: 1.4571x; 1.0515x over previous
//
#include <hip/hip_runtime.h>
#include <hip/hip_bf16.h>

typedef __bf16 bf16x8 __attribute__((ext_vector_type(8)));
typedef float  f32x4  __attribute__((ext_vector_type(4)));

#define SCHUNK 2048  // elements per scan1 block (256 thr * 8)

struct EdgeArgs {
    const int* ei[9];
    int E[9];
    int ebase[10];   // prefix over edges
    int binbase[9];  // prefix over dst bins
};

struct ConvGroup {          // 3 convs sharing the same dst type
    const int* rowptr[3];
    const __bf16* xsrc[3];
    const __bf16* agg[3];   // pre-gathered A (unfused convs)
    const __bf16* Wp[3];
    const float* bias[3];
    float* stats[3];
    __bf16* hout[3];
    const __bf16* xdst;
    const int* csr;
    int fused[3];
    int M;
};

struct NormGroup {
    const __bf16* h[3];
    const float* stats[3];
    const float* gamma[3];
    const float* beta[3];
    const float* resid;     // f32 base (L1) or null
    void* out;
    float invM;
    int M;
};

// ---------------------------------------------------------------- pack W
// Layout: [li=L*9+i][ks(8)][cf(8)][lane(64)][j(8)]  (bf16)
// k = ks*32 + (lane>>4)*8 + j ; col = cf*16 + (lane&15)
__global__ void __launch_bounds__(256) pack_w(const float* __restrict__ Wrel,
                                              const float* __restrict__ Wroot,
                                              __bf16* __restrict__ Wp)
{
    const int idx = blockIdx.x * 256 + threadIdx.x;
    if (idx >= 2 * 9 * 8 * 8 * 64) return;
    const int lane = idx & 63;
    int t = idx >> 6;
    const int cf = t & 7; t >>= 3;
    const int ks = t & 7; t >>= 3;
    const int li = t;  // 0..17
    const int col = cf * 16 + (lane & 15);
    const int kb  = ks * 32 + (lane >> 4) * 8;
    bf16x8 o;
#pragma unroll
    for (int j = 0; j < 8; ++j) {
        const int k = kb + j;
        const float v = (k < 128)
            ? Wrel [((size_t)li * 128 + k)        * 128 + col]
            : Wroot[((size_t)li * 128 + (k - 128)) * 128 + col];
        o[j] = (__bf16)v;
    }
    *reinterpret_cast<bf16x8*>(Wp + (size_t)idx * 8) = o;
}

// ---------------------------------------------------------------- f32 -> bf16 convert
__global__ void __launch_bounds__(256) cvt_kernel(const float* __restrict__ in,
                                                  __bf16* __restrict__ out, int n8)
{
    int i = blockIdx.x * 256 + threadIdx.x;
    const int stride = gridDim.x * 256;
    for (; i < n8; i += stride) {
        const float4 f0 = *reinterpret_cast<const float4*>(in + (size_t)i * 8);
        const float4 f1 = *reinterpret_cast<const float4*>(in + (size_t)i * 8 + 4);
        bf16x8 o;
        o[0] = (__bf16)f0.x; o[1] = (__bf16)f0.y; o[2] = (__bf16)f0.z; o[3] = (__bf16)f0.w;
        o[4] = (__bf16)f1.x; o[5] = (__bf16)f1.y; o[6] = (__bf16)f1.z; o[7] = (__bf16)f1.w;
        *reinterpret_cast<bf16x8*>(out + (size_t)i * 8) = o;
    }
}

// ---------------------------------------------------------------- CSR build
__global__ void __launch_bounds__(256) hist_kernel(EdgeArgs ea, int Etot,
                                                   int* __restrict__ deg)
{
    int g = blockIdx.x * 256 + threadIdx.x;
    const int stride = gridDim.x * 256;
    for (; g < Etot; g += stride) {
        int t = 0;
        while (g >= ea.ebase[t + 1]) ++t;
        const int e = g - ea.ebase[t];
        const int dst = __builtin_nontemporal_load(&ea.ei[t][ea.E[t] + e]);
        atomicAdd(&deg[ea.binbase[t] + dst], 1);
    }
}

__global__ void __launch_bounds__(256) scan1_kernel(const int* __restrict__ deg, int n,
                                                    int* __restrict__ rowptr,
                                                    int* __restrict__ bsum)
{
    __shared__ int lds[256];
    const int tid = threadIdx.x;
    const int base = blockIdx.x * SCHUNK + tid * 8;
    int v[8]; int tsum = 0;
#pragma unroll
    for (int j = 0; j < 8; ++j) { v[j] = (base + j < n) ? deg[base + j] : 0; tsum += v[j]; }
    int incl = tsum;
    lds[tid] = incl; __syncthreads();
    for (int off = 1; off < 256; off <<= 1) {
        const int add = (tid >= off) ? lds[tid - off] : 0;
        __syncthreads();
        incl += add; lds[tid] = incl; __syncthreads();
    }
    if (tid == 255) bsum[blockIdx.x] = incl;
    int run = incl - tsum;
#pragma unroll
    for (int j = 0; j < 8; ++j) { if (base + j < n) rowptr[base + j] = run; run += v[j]; }
}

__global__ void __launch_bounds__(256) scan2_kernel(int* __restrict__ bsum, int nb)
{
    __shared__ int lds[256];
    __shared__ int carry_s;
    const int tid = threadIdx.x;
    if (tid == 0) carry_s = 0;
    __syncthreads();
    for (int base = 0; base < nb; base += 256) {
        const int v = (base + tid < nb) ? bsum[base + tid] : 0;
        int incl = v;
        lds[tid] = incl; __syncthreads();
        for (int off = 1; off < 256; off <<= 1) {
            const int add = (tid >= off) ? lds[tid - off] : 0;
            __syncthreads();
            incl += add; lds[tid] = incl; __syncthreads();
        }
        const int total = lds[255];
        const int carry = carry_s;
        if (base + tid < nb) bsum[base + tid] = incl - v + carry;
        __syncthreads();
        if (tid == 0) carry_s = carry + total;
        __syncthreads();
    }
}

__global__ void __launch_bounds__(256) fixup_kernel(int* __restrict__ rowptr,
                                                    const int* __restrict__ bsum, int n,
                                                    int Etot, int* __restrict__ cursor)
{
    int i = blockIdx.x * 256 + threadIdx.x;
    const int stride = gridDim.x * 256;
    if (i == 0) rowptr[n] = Etot;
    for (; i < n; i += stride) {
        const int r = rowptr[i] + bsum[i >> 11];
        rowptr[i] = r; cursor[i] = r;
    }
}

// XCD-sharded placement; nontemporal edge reads keep the streaming re-read from
// evicting the shard's dirty cursor/csr lines out of L2.
__global__ void __launch_bounds__(256) place_kernel(EdgeArgs ea, int Etot, int Nbins,
                                                    int* __restrict__ cursor,
                                                    int* __restrict__ csr)
{
    const int shard = blockIdx.x & 7;
    const int lo = (int)(((long long)shard * Nbins) >> 3);
    const int hi = (int)(((long long)(shard + 1) * Nbins) >> 3);
    int g = (blockIdx.x >> 3) * 256 + threadIdx.x;
    const int stride = (gridDim.x >> 3) * 256;
    for (; g < Etot; g += stride) {
        int t = 0;
        while (g >= ea.ebase[t + 1]) ++t;
        const int e = g - ea.ebase[t];
        const int dst = __builtin_nontemporal_load(&ea.ei[t][ea.E[t] + e]);
        const int gb = ea.binbase[t] + dst;
        if (gb >= lo && gb < hi) {
            const int src = __builtin_nontemporal_load(&ea.ei[t][e]);
            const int pos = atomicAdd(&cursor[gb], 1);
            csr[pos] = src;
        }
    }
}

// ---------------------------------------------------------------- gather64
// wave per dst row (high-degree rows, dst=global): pairwise loads, 8 in flight/wave.
__global__ void __launch_bounds__(256) gather64(const __bf16* __restrict__ x,
                                                const int* __restrict__ rowptr,
                                                const int* __restrict__ csr,
                                                __bf16* __restrict__ agg, int N)
{
    const int lane = threadIdx.x & 63;
    const int l16 = lane & 15, grp = lane >> 4;
    int wv = (blockIdx.x * 256 + threadIdx.x) >> 6;
    const int nwv = (gridDim.x * 256) >> 6;
    for (int row = wv; row < N; row += nwv) {
        const int p0 = rowptr[row], p1 = rowptr[row + 1];
        float acc[8] = {0.f, 0.f, 0.f, 0.f, 0.f, 0.f, 0.f, 0.f};
        int p = p0 + grp * 2;
        for (; p + 2 <= p1; p += 8) {
            const int s0 = csr[p], s1 = csr[p + 1];
            const bf16x8 v0 = *reinterpret_cast<const bf16x8*>(x + (size_t)s0 * 128 + l16 * 8);
            const bf16x8 v1 = *reinterpret_cast<const bf16x8*>(x + (size_t)s1 * 128 + l16 * 8);
#pragma unroll
            for (int j = 0; j < 8; ++j) acc[j] += (float)v0[j] + (float)v1[j];
        }
        if (p < p1) {
            const int s0 = csr[p];
            const bf16x8 v0 = *reinterpret_cast<const bf16x8*>(x + (size_t)s0 * 128 + l16 * 8);
#pragma unroll
            for (int j = 0; j < 8; ++j) acc[j] += (float)v0[j];
        }
#pragma unroll
        for (int j = 0; j < 8; ++j) {
            acc[j] += __shfl_xor(acc[j], 16);
            acc[j] += __shfl_xor(acc[j], 32);
        }
        if (grp == 0) {
            bf16x8 o;
#pragma unroll
            for (int j = 0; j < 8; ++j) o[j] = (__bf16)acc[j];
            *reinterpret_cast<bf16x8*>(agg + (size_t)row * 128 + l16 * 8) = o;
        }
    }
}

// ---------------------------------------------------------------- batched fused gather+GEMM+stats
// R17 structure with TRANSPOSED GRID: blockIdx.x = conv j (fast-varying in
// dispatch order), blockIdx.y = row tile. The 3 convs of a tile now launch
// back-to-back in time, so their identical xdst rows (and a2a/b2b's xsrc
// overlap) are fetched once into L2/L3 and shared — R17's x-major order ran
// each conv slice to completion first, tripling the xdst HBM traffic
// (FETCH 183MB ~= 3x51 xdst + 30 random-miss).
__global__ void __launch_bounds__(256, 3) fgemm_group(ConvGroup cg)
{
    __shared__ __bf16 atile[128 * 128];   // 32 KB
    __shared__ float lsum[128];
    __shared__ float lsq[128];
    const int cj   = blockIdx.x;
    const int M    = cg.M;
    const int tid  = threadIdx.x;
    const int lane = tid & 63;
    const int wv   = tid >> 6;
    if (tid < 128) { lsum[tid] = 0.f; lsq[tid] = 0.f; }

    const int r0 = blockIdx.y * 128;
    const int lrow  = lane & 15;
    const int klane = (lane >> 4) * 8;

    int  car[2]; bool val[2];
#pragma unroll
    for (int rf = 0; rf < 2; ++rf) {
        const int ar = r0 + wv * 32 + rf * 16 + lrow;
        val[rf] = ar < M;
        car[rf] = val[rf] ? ar : (M - 1);
    }
    bf16x8 z8;
#pragma unroll
    for (int j = 0; j < 8; ++j) z8[j] = (__bf16)0.f;

    // early xdst fragment loads (k=128..255 half of A) — overlap with gather
    bf16x8 xd[2][4];
#pragma unroll
    for (int rf = 0; rf < 2; ++rf)
#pragma unroll
        for (int kk = 0; kk < 4; ++kk) {
            const bf16x8 av = *reinterpret_cast<const bf16x8*>(
                cg.xdst + (size_t)car[rf] * 128 + kk * 32 + klane);
            xd[rf][kk] = val[rf] ? av : z8;
        }

    const bool fused = cg.fused[cj] != 0;
    if (fused) {
        const int* __restrict__ rp  = cg.rowptr[cj];
        const int* __restrict__ csr = cg.csr;
        const __bf16* __restrict__ xsrc = cg.xsrc[cj];
        const int grp = tid >> 3, l8 = tid & 7;   // 32 groups of 8 lanes
        int pr[5];
#pragma unroll
        for (int rr = 0; rr < 5; ++rr) {
            int rw = r0 + grp * 4 + rr;
            pr[rr] = rp[rw > M ? M : rw];   // rows >= M collapse to empty ranges
        }
        // epoch 1: ALL csr-index loads (first 2 edges of each row), parallel
        int sA[4], sB[4];
#pragma unroll
        for (int rr = 0; rr < 4; ++rr) {
            const int p0 = pr[rr], p1 = pr[rr + 1];
            sA[rr] = (p0 < p1) ? csr[p0] : 0;
            sB[rr] = (p0 + 1 < p1) ? csr[p0 + 1] : sA[rr];
        }
        // epoch 2: ALL 16 row-data loads, parallel
        bf16x8 va0[4], va1[4], vb0[4], vb1[4];
#pragma unroll
        for (int rr = 0; rr < 4; ++rr) {
            const __bf16* a = xsrc + (size_t)sA[rr] * 128 + l8 * 16;
            const __bf16* b = xsrc + (size_t)sB[rr] * 128 + l8 * 16;
            va0[rr] = *reinterpret_cast<const bf16x8*>(a);
            va1[rr] = *reinterpret_cast<const bf16x8*>(a + 8);
            vb0[rr] = *reinterpret_cast<const bf16x8*>(b);
            vb1[rr] = *reinterpret_cast<const bf16x8*>(b + 8);
        }
        // epoch 3: accumulate + rare tails (deg>2) + swizzled LDS store
#pragma unroll
        for (int rr = 0; rr < 4; ++rr) {
            const int lr = grp * 4 + rr;
            const int p0 = pr[rr], p1 = pr[rr + 1];
            const int deg = p1 - p0;
            float acc[16];
#pragma unroll
            for (int j = 0; j < 16; ++j) acc[j] = 0.f;
            if (deg > 0) {
#pragma unroll
                for (int j = 0; j < 8; ++j) {
                    acc[j]     += (float)va0[rr][j];
                    acc[8 + j] += (float)va1[rr][j];
                }
            }
            if (deg > 1) {
#pragma unroll
                for (int j = 0; j < 8; ++j) {
                    acc[j]     += (float)vb0[rr][j];
                    acc[8 + j] += (float)vb1[rr][j];
                }
            }
            for (int p = p0 + 2; p < p1; p += 2) {   // tail, pairwise
                const int s0 = csr[p];
                const int s1 = (p + 1 < p1) ? csr[p + 1] : s0;
                const float m1 = (p + 1 < p1) ? 1.f : 0.f;
                const __bf16* a = xsrc + (size_t)s0 * 128 + l8 * 16;
                const __bf16* b = xsrc + (size_t)s1 * 128 + l8 * 16;
                const bf16x8 t0 = *reinterpret_cast<const bf16x8*>(a);
                const bf16x8 t1 = *reinterpret_cast<const bf16x8*>(a + 8);
                const bf16x8 t2 = *reinterpret_cast<const bf16x8*>(b);
                const bf16x8 t3 = *reinterpret_cast<const bf16x8*>(b + 8);
#pragma unroll
                for (int j = 0; j < 8; ++j) {
                    acc[j]     += (float)t0[j] + m1 * (float)t2[j];
                    acc[8 + j] += (float)t1[j] + m1 * (float)t3[j];
                }
            }
            bf16x8 o0, o1;
#pragma unroll
            for (int j = 0; j < 8; ++j) { o0[j] = (__bf16)acc[j]; o1[j] = (__bf16)acc[8 + j]; }
            // swizzle at 16B-chunk granularity: chunk cb -> cb ^ (lr&7)
            char* base = (char*)atile + lr * 256;
            *reinterpret_cast<bf16x8*>(base + (((l8 * 2    ) << 4) ^ ((lr & 7) << 4))) = o0;
            *reinterpret_cast<bf16x8*>(base + (((l8 * 2 + 1) << 4) ^ ((lr & 7) << 4))) = o1;
        }
    }
    __syncthreads();

    f32x4 acc[2][8];
#pragma unroll
    for (int rf = 0; rf < 2; ++rf)
#pragma unroll
        for (int cf = 0; cf < 8; ++cf) {
            f32x4 z; z[0] = 0.f; z[1] = 0.f; z[2] = 0.f; z[3] = 0.f;
            acc[rf][cf] = z;
        }

    const __bf16* __restrict__ aggp = cg.agg[cj];
    const __bf16* __restrict__ Wp   = cg.Wp[cj];
#pragma unroll
    for (int ks = 0; ks < 8; ++ks) {
        const int koff = (ks & 3) * 32 + klane;
        bf16x8 a[2];
#pragma unroll
        for (int rf = 0; rf < 2; ++rf) {
            if (ks < 4) {
                if (fused) {
                    const int lr = wv * 32 + rf * 16 + lrow;
                    const char* sp = (const char*)atile + lr * 256
                                   + ((koff * 2) ^ ((lr & 7) << 4));
                    a[rf] = *reinterpret_cast<const bf16x8*>(sp);
                } else {
                    const bf16x8 av = *reinterpret_cast<const bf16x8*>(
                        aggp + (size_t)car[rf] * 128 + koff);
                    a[rf] = val[rf] ? av : z8;
                }
            } else {
                a[rf] = xd[rf][ks - 4];
            }
        }
        const bf16x8* wp8 = reinterpret_cast<const bf16x8*>(Wp) + (size_t)ks * 8 * 64 + lane;
        bf16x8 b[8];
#pragma unroll
        for (int cf = 0; cf < 8; ++cf) b[cf] = wp8[(size_t)cf * 64];
#pragma unroll
        for (int rf = 0; rf < 2; ++rf)
#pragma unroll
            for (int cf = 0; cf < 8; ++cf)
                acc[rf][cf] = __builtin_amdgcn_mfma_f32_16x16x32_bf16(a[rf], b[cf], acc[rf][cf], 0, 0, 0);
    }

    const float* __restrict__ bias = cg.bias[cj];
    __bf16* __restrict__ hout = cg.hout[cj];
    float bc[8];
#pragma unroll
    for (int cf = 0; cf < 8; ++cf) bc[cf] = bias[cf * 16 + lrow];

    const int rb = (lane >> 4) * 4;
#pragma unroll
    for (int cf = 0; cf < 8; ++cf) {
        float s = 0.f, q = 0.f;
#pragma unroll
        for (int rf = 0; rf < 2; ++rf) {
#pragma unroll
            for (int rr = 0; rr < 4; ++rr) {
                const int grow = r0 + wv * 32 + rf * 16 + rb + rr;
                if (grow < M) {
                    const float hv = acc[rf][cf][rr] + bc[cf];
                    hout[(size_t)grow * 128 + cf * 16 + lrow] = (__bf16)hv;
                    s += hv; q += hv * hv;
                }
            }
        }
        s += __shfl_xor(s, 16); s += __shfl_xor(s, 32);
        q += __shfl_xor(q, 16); q += __shfl_xor(q, 32);
        if (lane < 16) {
            atomicAdd(&lsum[cf * 16 + lane], s);
            atomicAdd(&lsq [cf * 16 + lane], q);
        }
    }
    __syncthreads();
    float* __restrict__ st = cg.stats[cj];
    if (tid < 128) {
        atomicAdd(&st[tid],       lsum[tid]);
        atomicAdd(&st[128 + tid], lsq[tid]);
    }
}

// ---------------------------------------------------------------- batched normalize + sum 3 convs
// out = base + sum_j gamma_j*(h_j-mu_j)*rsqrt(var_j+eps)+beta_j ; base = 0 (L0/bf16) or resid (L1/f32)
template<bool F32OUT>
__global__ void __launch_bounds__(256) norm_group(NormGroup ng)
{
    __shared__ float ssc[3][128], ssh[3][128];
    const int tid = threadIdx.x;
    if (tid < 128) {
#pragma unroll
        for (int j = 0; j < 3; ++j) {
            const float mu   = ng.stats[j][tid] * ng.invM;
            const float var  = ng.stats[j][128 + tid] * ng.invM - mu * mu;
            const float scal = ng.gamma[j][tid] * rsqrtf(var + 1e-5f);
            ssc[j][tid] = scal;
            ssh[j][tid] = ng.beta[j][tid] - mu * scal;
        }
    }
    __syncthreads();

    const int t0   = blockIdx.x * 256 + tid;
    const int nthr = gridDim.x * 256;
    const int c0   = (t0 & 15) * 8;
    float sc[3][8], sh[3][8];
#pragma unroll
    for (int j = 0; j < 3; ++j)
#pragma unroll
        for (int k = 0; k < 8; ++k) { sc[j][k] = ssc[j][c0 + k]; sh[j][k] = ssh[j][c0 + k]; }

    const int nch = ng.M * 16;
    for (int ch = t0; ch < nch; ch += nthr) {
        float f[8] = {0.f, 0.f, 0.f, 0.f, 0.f, 0.f, 0.f, 0.f};
#pragma unroll
        for (int j = 0; j < 3; ++j) {
            const bf16x8 hv = *reinterpret_cast<const bf16x8*>(ng.h[j] + (size_t)ch * 8);
#pragma unroll
            for (int k = 0; k < 8; ++k) f[k] += (float)hv[k] * sc[j][k] + sh[j][k];
        }
        if constexpr (F32OUT) {
            const float* rp = ng.resid + (size_t)ch * 8;
            const float4 r0 = *reinterpret_cast<const float4*>(rp);
            const float4 r1 = *reinterpret_cast<const float4*>(rp + 4);
            float* op = (float*)ng.out + (size_t)ch * 8;
            float4 o0, o1;
            o0.x = r0.x + f[0]; o0.y = r0.y + f[1]; o0.z = r0.z + f[2]; o0.w = r0.w + f[3];
            o1.x = r1.x + f[4]; o1.y = r1.y + f[5]; o1.z = r1.z + f[6]; o1.w = r1.w + f[7];
            *reinterpret_cast<float4*>(op)     = o0;
            *reinterpret_cast<float4*>(op + 4) = o1;
        } else {
            bf16x8 ov;
#pragma unroll
            for (int k = 0; k < 8; ++k) ov[k] = (__bf16)f[k];
            *reinterpret_cast<bf16x8*>((__bf16*)ng.out + (size_t)ch * 8) = ov;
        }
    }
}

// ---------------------------------------------------------------- launch
extern "C" void kernel_launch(void* const* d_in, const int* in_sizes, int n_in,
                              void* d_out, int out_size, void* d_ws, size_t ws_size,
                              hipStream_t stream)
{
    const float* xin[3] = {(const float*)d_in[0], (const float*)d_in[1], (const float*)d_in[2]};
    const int N[3] = {in_sizes[0] / 128, in_sizes[1] / 128, in_sizes[2] / 128};
    const float* Wrel  = (const float*)d_in[12];
    const float* brel  = (const float*)d_in[13];
    const float* Wroot = (const float*)d_in[14];
    const float* gamma = (const float*)d_in[15];
    const float* beta  = (const float*)d_in[16];

    // ETS order: a2b b2a a2g g2a b2g g2b a2a b2b g2g  (atom=0,bond=1,global=2)
    const int cs[9] = {0, 1, 0, 2, 1, 2, 0, 1, 2};
    const int cd[9] = {1, 0, 2, 0, 2, 1, 0, 1, 2};
    // dst-groups: convs (ETS idx) per dst type
    const int gconv[3][3] = {{1, 3, 6},   // dst=atom : b2a, g2a, a2a
                             {0, 5, 7},   // dst=bond : a2b, g2b, b2b
                             {2, 4, 8}};  // dst=global: a2g, b2g, g2g

    const size_t nA = (size_t)N[0] * 128, nB = (size_t)N[1] * 128, nG = (size_t)N[2] * 128;
    const size_t off[3] = {0, nA, nA + nB};
    const size_t xtot = nA + nB + nG;
    size_t maxN = (size_t)N[0];
    if ((size_t)N[1] > maxN) maxN = N[1];
    if ((size_t)N[2] > maxN) maxN = N[2];

    // edge/bin geometry
    EdgeArgs ea;
    int Etot = 0, Nbins = 0;
    ea.ebase[0] = 0;
    for (int t = 0; t < 9; ++t) {
        ea.ei[t] = (const int*)d_in[3 + t];
        ea.E[t]  = in_sizes[3 + t] / 2;
        ea.ebase[t + 1] = ea.ebase[t] + ea.E[t];
        ea.binbase[t] = Nbins;
        Nbins += N[cd[t]];
    }
    Etot = ea.ebase[9];
    const int nb1 = (Nbins + SCHUNK - 1) / SCHUNK;

    // ws layout (~410 MB)
    auto al = [](size_t x) { return (x + 15) & ~(size_t)15; };
    char* w = (char*)d_ws;
    __bf16* x0b   = (__bf16*)w;  w += al(xtot * 2);
    __bf16* x1    = (__bf16*)w;  w += al(xtot * 2);
    __bf16* aggb  = (__bf16*)w;  w += al(2 * maxN * 128 * 2);
    __bf16* hbuf  = (__bf16*)w;  w += al(3 * maxN * 128 * 2);
    float*  stats = (float*)w;   w += al(18 * 256 * 4);
    __bf16* Wp    = (__bf16*)w;  w += al((size_t)18 * 32768 * 2);
    int*    deg   = (int*)w;     w += al((size_t)Nbins * 4);
    int*    rowptr= (int*)w;     w += al(((size_t)Nbins + 1) * 4);
    int*    cursor= (int*)w;     w += al((size_t)Nbins * 4);
    int*    csr   = (int*)w;     w += al((size_t)Etot * 4);
    int*    bsum  = (int*)w;     w += al((size_t)nb1 * 4);
    (void)ws_size; (void)n_in; (void)out_size;

    pack_w<<<288, 256, 0, stream>>>(Wrel, Wroot, Wp);
    for (int k = 0; k < 3; ++k) {
        const int n8 = (int)(((k == 0 ? nA : k == 1 ? nB : nG)) / 8);
        int cb = (n8 + 255) / 256; if (cb > 2048) cb = 2048;
        cvt_kernel<<<cb, 256, 0, stream>>>(xin[k], x0b + off[k], n8);
    }
    hipMemsetAsync(deg, 0, (size_t)Nbins * 4, stream);
    hipMemsetAsync(stats, 0, 18 * 256 * 4, stream);

    int eb = (Etot + 255) / 256; if (eb > 2048) eb = 2048;
    hist_kernel<<<eb, 256, 0, stream>>>(ea, Etot, deg);
    scan1_kernel<<<nb1, 256, 0, stream>>>(deg, Nbins, rowptr, bsum);
    scan2_kernel<<<1, 256, 0, stream>>>(bsum, nb1);
    int fb = (Nbins + 255) / 256; if (fb > 2048) fb = 2048;
    fixup_kernel<<<fb, 256, 0, stream>>>(rowptr, bsum, Nbins, Etot, cursor);
    place_kernel<<<2048, 256, 0, stream>>>(ea, Etot, Nbins, cursor, csr);

    float* dout = (float*)d_out;

    for (int L = 0; L < 2; ++L) {
        const __bf16* xb = (L == 0) ? x0b : x1;

        // pre-gather high-degree (deg>=8) convs: a2g (ets 2), b2g (ets 4)
        {
            const int Ng = N[2];
            int gb2 = (Ng * 64 + 255) / 256; if (gb2 > 2048) gb2 = 2048; if (gb2 < 1) gb2 = 1;
            gather64<<<gb2, 256, 0, stream>>>(xb + off[0], rowptr + ea.binbase[2], csr,
                                              aggb, Ng);
            gather64<<<gb2, 256, 0, stream>>>(xb + off[1], rowptr + ea.binbase[4], csr,
                                              aggb + maxN * 128, Ng);
        }

        for (int g = 0; g < 3; ++g) {
            const int d  = g;           // dst type == group index
            const int Nd = N[d];
            ConvGroup cg;
            NormGroup ng;
            cg.xdst = xb + off[d];
            cg.csr  = csr;
            cg.M    = Nd;
            for (int j = 0; j < 3; ++j) {
                const int et = gconv[g][j];
                const int li = L * 9 + et;
                cg.rowptr[j] = rowptr + ea.binbase[et];
                cg.xsrc[j]   = xb + off[cs[et]];
                cg.Wp[j]     = Wp + (size_t)li * 32768;
                cg.bias[j]   = brel + li * 128;
                cg.stats[j]  = stats + li * 256;
                cg.hout[j]   = hbuf + (size_t)j * maxN * 128;
                const bool hi = (et == 2) || (et == 4);
                cg.fused[j]  = hi ? 0 : 1;
                cg.agg[j]    = (et == 2) ? aggb : (et == 4 ? aggb + maxN * 128 : (const __bf16*)nullptr);
                ng.h[j]      = cg.hout[j];
                ng.stats[j]  = cg.stats[j];
                ng.gamma[j]  = gamma + li * 128;
                ng.beta[j]   = beta + li * 128;
            }
            const int gb = (Nd + 127) / 128;
            fgemm_group<<<dim3(3, gb), 256, 0, stream>>>(cg);

            ng.invM = 1.0f / (float)Nd;
            ng.M    = Nd;
            const long long nch = (long long)Nd * 16;
            int nb = (int)((nch + 255) / 256); if (nb > 2048) nb = 2048;
            if (L == 0) {
                ng.resid = nullptr;
                ng.out   = (void*)(x1 + off[d]);
                norm_group<false><<<nb, 256, 0, stream>>>(ng);
            } else {
                ng.resid = xin[d];
                ng.out   = (void*)(dout + off[d]);
                norm_group<true><<<nb, 256, 0, stream>>>(ng);
            }
        }
    }
}